// Round 10
// baseline (440.089 us; speedup 1.0000x reference)
//
#include <hip/hip_runtime.h>

// ---------------------------------------------------------------------------
// Mamba2 hybrid block. GEMMs: bf16 MFMA 16x16x32, f32 accumulate, m97-style
// global_load_lds(16B) staging with XOR bank swizzle. Small-N GEMMs use
// split-K x4 into SEPARATE partial buffers (plain stores, no atomics);
// partials summed inside the downstream residual_rms kernel. Scan: 3-phase
// chunked, CHUNK=32; B/C staged in LDS as BF16 (R9: f32 LDS broadcast reads
// were the phase2 bottleneck — 16 b128/step ≈ 86% of wall; bf16 halves it
// and kills the 64-reg double-buffer). y per-lane complete, plain stores.
// ---------------------------------------------------------------------------

#define BB 4
#define LL 1024
#define DMODEL 512
#define DINNER 1024
#define NHEADS 16
#define HEADDIM 64
#define DSTATE 64
#define CONVDIM 1152        // DINNER + 2*DSTATE
#define NPROJ 2192          // D_IN_PROJ
#define NPROJ_PAD 2304      // padded to multiple of 128
#define INTER_T 2816
#define INTER_M 1536
#define NCHUNK 32
#define CHUNK 32

typedef __bf16 bf16x8 __attribute__((ext_vector_type(8)));
typedef float  f32x4  __attribute__((ext_vector_type(4)));
typedef unsigned short u16;
typedef unsigned int   u32;

__device__ __forceinline__ u16 f2bf(float x) {
    union { float f; u32 u; } v; v.f = x;
    u32 u = v.u;
    return (u16)((u + 0x7fffu + ((u >> 16) & 1u)) >> 16);
}
__device__ __forceinline__ float silu_f(float x) {
    return x / (1.f + __expf(-x));
}
// unpack 2 bf16 from one u32 word (little-endian: low half = even element)
__device__ __forceinline__ void bf2f2(u32 w, float& lo, float& hi) {
    union { u32 u; float f; } a, b;
    a.u = w << 16; b.u = w & 0xffff0000u;
    lo = a.f; hi = b.f;
}

// async global->LDS, 16B per lane; LDS dest is wave-uniform base + lane*16
__device__ __forceinline__ void gld_lds16(const u16* g, u16* l) {
    __builtin_amdgcn_global_load_lds(
        (const __attribute__((address_space(1))) unsigned int*)g,
        (__attribute__((address_space(3))) unsigned int*)l, 16, 0, 0);
}

// --------------------------- block-wide sum --------------------------------
__device__ __forceinline__ float block_sum(float v) {
    #pragma unroll
    for (int off = 32; off > 0; off >>= 1) v += __shfl_xor(v, off, 64);
    __shared__ float red[4];
    int w = threadIdx.x >> 6;
    int nwv = blockDim.x >> 6;
    if ((threadIdx.x & 63) == 0) red[w] = v;
    __syncthreads();
    float tot = red[0];
    for (int i = 1; i < nwv; i++) tot += red[i];
    return tot;
}

// --------------------- f32 -> bf16 convert (all weights + hidden) ----------
#define HID_E      2097152LL   // 4096*512
#define INPROJ_P_E 1179648LL   // 2304*512
#define INPROJ_S_E 1122304LL   // 2192*512
#define OUTPROJ_E   524288LL   // 512*1024
#define GUT_E      5767168LL   // 5632*1024
#define DOWNT_E    2883584LL   // 1024*2816
#define GUM_E      1572864LL   // 3072*512
#define DOWNM_E     786432LL   // 512*1536
#define CONV_TOT_E 14811136LL

__global__ __launch_bounds__(256) void convert_all_kernel(
    const float* __restrict__ s_hid, const float* __restrict__ s_inproj,
    const float* __restrict__ s_outproj, const float* __restrict__ s_gut,
    const float* __restrict__ s_downt, const float* __restrict__ s_gum,
    const float* __restrict__ s_downm, u16* __restrict__ dst)
{
    long long idx = (long long)blockIdx.x * 256 + threadIdx.x;
    long long e = idx * 4;
    if (e >= CONV_TOT_E) return;
    const float* src; long long off, nsrc;
    long long c0 = HID_E;
    long long c1 = c0 + INPROJ_P_E;
    long long c2 = c1 + OUTPROJ_E;
    long long c3 = c2 + GUT_E;
    long long c4 = c3 + DOWNT_E;
    long long c5 = c4 + GUM_E;
    if      (e < c0) { src = s_hid;     off = e;      nsrc = HID_E; }
    else if (e < c1) { src = s_inproj;  off = e - c0; nsrc = INPROJ_S_E; }
    else if (e < c2) { src = s_outproj; off = e - c1; nsrc = OUTPROJ_E; }
    else if (e < c3) { src = s_gut;     off = e - c2; nsrc = GUT_E; }
    else if (e < c4) { src = s_downt;   off = e - c3; nsrc = DOWNT_E; }
    else if (e < c5) { src = s_gum;     off = e - c4; nsrc = GUM_E; }
    else             { src = s_downm;   off = e - c5; nsrc = DOWNM_E; }
    ushort4 r;
    if (off < nsrc) {
        float4 v = *reinterpret_cast<const float4*>(src + off);
        r.x = f2bf(v.x); r.y = f2bf(v.y); r.z = f2bf(v.z); r.w = f2bf(v.w);
    } else {
        r.x = 0; r.y = 0; r.z = 0; r.w = 0;
    }
    *reinterpret_cast<ushort4*>(dst + e) = r;
}

// ----------------------------- bf16 MFMA GEMM ------------------------------
// C[M,N] = A[M,K] * W[N,K]^T. 128x128 tile, 4 waves of 64x64 (4x4 MFMAs).
// global_load_lds staging (no pad; XOR chunk swizzle vs bank conflicts).
// SK: write this slice's tile to C + slice*M*N (plain stores; summed later).
template<bool SK>
__device__ __forceinline__ void gemm_bt_body(
    const u16* __restrict__ A, const u16* __restrict__ W,
    float* __restrict__ C, int M, int N, int K, int kLen)
{
    __shared__ u16 As[128 * 32];
    __shared__ u16 Bs[128 * 32];
    int tid = threadIdx.x;
    int m0 = blockIdx.y * 128, n0 = blockIdx.x * 128;
    int kBase = SK ? blockIdx.z * kLen : 0;
    float* Cw = SK ? C + (size_t)blockIdx.z * M * N : C;
    int wave = tid >> 6, lane = tid & 63;
    int wm = (wave >> 1) * 64, wn = (wave & 1) * 64;
    int lrow = lane & 15;
    int kq = lane >> 4;
    int kx = (lrow & 3) ^ ((lrow >> 2) & 3);
    int ko = (kq ^ kx) * 8;           // swizzled LDS chunk offset for frags

    int rL = lane >> 2, cL = lane & 3;
    int cG = cL ^ ((rL & 3) ^ ((rL >> 2) & 3));
    int R0 = wave * 32 + rL;
    int R1 = R0 + 16;
    const u16* gA0 = A + (size_t)(m0 + R0) * K + kBase + cG * 8;
    const u16* gA1 = A + (size_t)(m0 + R1) * K + kBase + cG * 8;
    const u16* gB0 = W + (size_t)(n0 + R0) * K + kBase + cG * 8;
    const u16* gB1 = W + (size_t)(n0 + R1) * K + kBase + cG * 8;
    u16* lA0 = &As[(wave * 32) * 32];
    u16* lA1 = &As[(wave * 32 + 16) * 32];
    u16* lB0 = &Bs[(wave * 32) * 32];
    u16* lB1 = &Bs[(wave * 32 + 16) * 32];

    f32x4 acc[4][4];
    #pragma unroll
    for (int i = 0; i < 4; i++)
        #pragma unroll
        for (int j = 0; j < 4; j++) {
            acc[i][j][0] = 0.f; acc[i][j][1] = 0.f;
            acc[i][j][2] = 0.f; acc[i][j][3] = 0.f;
        }

    for (int kt = 0; kt < kLen; kt += 32) {
        __syncthreads();
        gld_lds16(gA0 + kt, lA0);
        gld_lds16(gA1 + kt, lA1);
        gld_lds16(gB0 + kt, lB0);
        gld_lds16(gB1 + kt, lB1);
        __syncthreads();
        bf16x8 af[4], bfr[4];
        #pragma unroll
        for (int i = 0; i < 4; i++) {
            af[i]  = *reinterpret_cast<const bf16x8*>(&As[(wm + i * 16 + lrow) * 32 + ko]);
            bfr[i] = *reinterpret_cast<const bf16x8*>(&Bs[(wn + i * 16 + lrow) * 32 + ko]);
        }
        #pragma unroll
        for (int i = 0; i < 4; i++)
            #pragma unroll
            for (int j = 0; j < 4; j++)
                acc[i][j] = __builtin_amdgcn_mfma_f32_16x16x32_bf16(af[i], bfr[j], acc[i][j], 0, 0, 0);
    }

    // C/D layout: col = lane&15, row = (lane>>4)*4 + reg
    int rbase = m0 + wm + kq * 4;
    int cbase = n0 + wn + lrow;
    #pragma unroll
    for (int i = 0; i < 4; i++)
        #pragma unroll
        for (int j = 0; j < 4; j++)
            #pragma unroll
            for (int r = 0; r < 4; r++)
                Cw[(size_t)(rbase + i * 16 + r) * N + cbase + j * 16] = acc[i][j][r];
}

__global__ __launch_bounds__(256) void gemm_bt(
    const u16* __restrict__ A, const u16* __restrict__ W,
    float* __restrict__ C, int M, int N, int K)
{
    gemm_bt_body<false>(A, W, C, M, N, K, K);
}

__global__ __launch_bounds__(256) void gemm_bt_sk(
    const u16* __restrict__ A, const u16* __restrict__ W,
    float* __restrict__ C, int M, int N, int K, int kLen)
{
    gemm_bt_body<true>(A, W, C, M, N, K, kLen);
}

// ----------------- conv (depthwise, causal, width 4) + dt ------------------
__global__ __launch_bounds__(256) void conv_dt_kernel(
    const float* __restrict__ zx, const float* __restrict__ conv_w,
    const float* __restrict__ conv_b, const float* __restrict__ dt_bias,
    float* __restrict__ convout, float* __restrict__ dtbuf)
{
    int idx = blockIdx.x * 256 + threadIdx.x;   // over 4096*1168
    int bl = idx / 1168;
    int c  = idx - bl * 1168;
    int l  = bl & (LL - 1);
    if (c < CONVDIM) {
        const float* col = zx + (size_t)bl * NPROJ_PAD + DINNER + c;
        float acc = conv_b[c];
        #pragma unroll
        for (int i = 0; i < 4; i++) {
            int lt = l - 3 + i;
            float v = (lt >= 0) ? col[(long long)(lt - l) * NPROJ_PAD] : 0.f;
            acc = fmaf(v, conv_w[c * 4 + i], acc);
        }
        convout[(size_t)bl * CONVDIM + c] = silu_f(acc);
    } else {
        int h = c - CONVDIM;
        float v = zx[(size_t)bl * NPROJ_PAD + 2176 + h] + dt_bias[h];
        float sp = (v > 20.f) ? v : log1pf(__expf(v));
        dtbuf[(size_t)bl * NHEADS + h] = sp;
    }
}

// ----------------------- chunked SSM scan: phase 1 -------------------------
// block = (b*16+h)*32 + c, 256 thr; wave = nq (16 states/lane); B (bf16) + dt
// staged in LDS once per chunk. 32 steps from zero state -> Sc, Ptot.
__global__ __launch_bounds__(256) void scan_phase1(
    const float* __restrict__ convout, const float* __restrict__ dtbuf,
    const float* __restrict__ A_log, float* __restrict__ Sc,
    float* __restrict__ Ptot)
{
    __shared__ u16 Blds[CHUNK * 64];     // 4 KB, bf16
    __shared__ float dtl[CHUNK];
    int blk = blockIdx.x;
    int c   = blk & 31;
    int bh  = blk >> 5;
    int b = bh >> 4, h = bh & 15;
    int nq = threadIdx.x >> 6;
    int p  = threadIdx.x & 63;
    size_t base = ((size_t)b * LL + (size_t)c * CHUNK) * CONVDIM;

    const float* Bsrc = convout + base + DINNER;
    #pragma unroll
    for (int i = threadIdx.x; i < CHUNK * 16; i += 256) {   // 512 float4s
        int t = i >> 4, q = i & 15;
        float4 v = *reinterpret_cast<const float4*>(&Bsrc[(size_t)t * CONVDIM + q * 4]);
        ushort4 r; r.x = f2bf(v.x); r.y = f2bf(v.y); r.z = f2bf(v.z); r.w = f2bf(v.w);
        *reinterpret_cast<ushort4*>(&Blds[t * 64 + q * 4]) = r;
    }
    const float* db = dtbuf + ((size_t)b * LL + (size_t)c * CHUNK) * NHEADS + h;
    if (threadIdx.x < CHUNK) dtl[threadIdx.x] = db[(size_t)threadIdx.x * NHEADS];
    __syncthreads();

    float Ah = -__expf(A_log[h]);
    const float* xb = convout + base + h * HEADDIM + p;

    float s[16];
    #pragma unroll
    for (int j = 0; j < 16; j++) s[j] = 0.f;
    float dtsum = 0.f;

    float xvc = xb[0];
    for (int t = 0; t < CHUNK; ++t) {
        float dt = dtl[t];
        float xv = xvc;
        int tn = (t < CHUNK - 1) ? t + 1 : CHUNK - 1;
        xvc = xb[(size_t)tn * CONVDIM];
        const uint4* Bp = reinterpret_cast<const uint4*>(&Blds[t * 64 + nq * 16]);
        uint4 b0 = Bp[0], b1 = Bp[1];
        u32 Bw[8] = { b0.x, b0.y, b0.z, b0.w, b1.x, b1.y, b1.z, b1.w };
        float dA = __expf(dt * Ah);
        dtsum += dt;
        float coef = dt * xv;
        #pragma unroll
        for (int w = 0; w < 8; w++) {
            float lo, hi; bf2f2(Bw[w], lo, hi);
            s[2 * w]     = fmaf(s[2 * w],     dA, coef * lo);
            s[2 * w + 1] = fmaf(s[2 * w + 1], dA, coef * hi);
        }
    }
    float* So = Sc + ((size_t)(bh * 4 + nq) * NCHUNK + c) * 1024 + p * 16;
    #pragma unroll
    for (int q = 0; q < 4; q++) {
        float4 v; v.x = s[q*4]; v.y = s[q*4+1]; v.z = s[q*4+2]; v.w = s[q*4+3];
        *reinterpret_cast<float4*>(So + q * 4) = v;
    }
    if (nq == 0 && p == 0) Ptot[bh * NCHUNK + c] = __expf(Ah * dtsum);
}

// ----------------------- chunked SSM scan: phase 2 -------------------------
// block = (b*16+h)*4 + nq (256 blocks); sequential carry over 32 chunks.
__global__ __launch_bounds__(64) void scan_combine(
    const float* __restrict__ Sc, const float* __restrict__ Ptot,
    float* __restrict__ Sinit)
{
    int blk = blockIdx.x;
    int bh = blk >> 2;
    int p = threadIdx.x;
    float carry[16];
    #pragma unroll
    for (int j = 0; j < 16; j++) carry[j] = 0.f;
    for (int c = 0; c < NCHUNK; ++c) {
        size_t row = ((size_t)blk * NCHUNK + c) * 1024 + p * 16;
        float* o = Sinit + row;
        #pragma unroll
        for (int j = 0; j < 16; j++) o[j] = carry[j];
        float P = Ptot[bh * NCHUNK + c];
        const float* si = Sc + row;
        #pragma unroll
        for (int j = 0; j < 16; j++) carry[j] = fmaf(carry[j], P, si[j]);
    }
}

// ----------------------- chunked SSM scan: phase 3 -------------------------
// block = (b*16+h)*32 + c, 128 thr; wave = nh (32 states/lane). B+C (bf16)
// + dt staged in LDS; per step: 8 b128 broadcast reads + in-reg bf16 unpack.
// y per-lane complete -> plain coalesced stores into yp0/yp1.
__global__ __launch_bounds__(128) void scan_phase2(
    const float* __restrict__ convout, const float* __restrict__ dtbuf,
    const float* __restrict__ A_log, const float* __restrict__ Sinit,
    float* __restrict__ yp0, float* __restrict__ yp1)
{
    __shared__ u16 BClds[CHUNK * 128];   // 8 KB, bf16 (B 64 | C 64 per step)
    __shared__ float dtl[CHUNK];
    int blk = blockIdx.x;
    int c   = blk & 31;
    int bh  = blk >> 5;
    int b = bh >> 4, h = bh & 15;
    int nh = threadIdx.x >> 6;
    int p  = threadIdx.x & 63;
    size_t base = ((size_t)b * LL + (size_t)c * CHUNK) * CONVDIM;

    const float* BCsrc = convout + base + DINNER;
    #pragma unroll
    for (int i = threadIdx.x; i < CHUNK * 32; i += 128) {   // 1024 float4s
        int t = i >> 5, q = i & 31;
        float4 v = *reinterpret_cast<const float4*>(&BCsrc[(size_t)t * CONVDIM + q * 4]);
        ushort4 r; r.x = f2bf(v.x); r.y = f2bf(v.y); r.z = f2bf(v.z); r.w = f2bf(v.w);
        *reinterpret_cast<ushort4*>(&BClds[t * 128 + q * 4]) = r;
    }
    const float* db = dtbuf + ((size_t)b * LL + (size_t)c * CHUNK) * NHEADS + h;
    if (threadIdx.x < CHUNK) dtl[threadIdx.x] = db[(size_t)threadIdx.x * NHEADS];
    __syncthreads();

    float Ah = -__expf(A_log[h]);
    const float* xb = convout + base + h * HEADDIM + p;
    float* yb = (nh ? yp1 : yp0)
              + ((size_t)b * LL + (size_t)c * CHUNK) * DINNER + h * HEADDIM + p;

    float s[32];
    {   // states j<16 from quarter 2*nh, j>=16 from quarter 2*nh+1
        const float* si0 = Sinit + ((size_t)(bh * 4 + nh * 2)     * NCHUNK + c) * 1024 + p * 16;
        const float* si1 = Sinit + ((size_t)(bh * 4 + nh * 2 + 1) * NCHUNK + c) * 1024 + p * 16;
        #pragma unroll
        for (int j = 0; j < 16; j++) { s[j] = si0[j]; s[16 + j] = si1[j]; }
    }

    float xvc = xb[0];
    for (int t = 0; t < CHUNK; ++t) {
        float dt = dtl[t];
        float xv = xvc;
        int tn = (t < CHUNK - 1) ? t + 1 : CHUNK - 1;
        xvc = xb[(size_t)tn * CONVDIM];
        const uint4* Bp = reinterpret_cast<const uint4*>(&BClds[t * 128 + nh * 32]);
        const uint4* Cp = reinterpret_cast<const uint4*>(&BClds[t * 128 + 64 + nh * 32]);
        uint4 b0 = Bp[0], b1 = Bp[1], b2 = Bp[2], b3 = Bp[3];
        uint4 c0 = Cp[0], c1 = Cp[1], c2 = Cp[2], c3 = Cp[3];
        u32 Bw[16] = { b0.x,b0.y,b0.z,b0.w, b1.x,b1.y,b1.z,b1.w,
                       b2.x,b2.y,b2.z,b2.w, b3.x,b3.y,b3.z,b3.w };
        u32 Cw[16] = { c0.x,c0.y,c0.z,c0.w, c1.x,c1.y,c1.z,c1.w,
                       c2.x,c2.y,c2.z,c2.w, c3.x,c3.y,c3.z,c3.w };
        float dA = __expf(dt * Ah);
        float coef = dt * xv;
        float yacc = 0.f;
        #pragma unroll
        for (int w = 0; w < 16; w++) {
            float blo, bhi, clo, chi;
            bf2f2(Bw[w], blo, bhi);
            bf2f2(Cw[w], clo, chi);
            s[2 * w]     = fmaf(s[2 * w],     dA, coef * blo);
            yacc         = fmaf(s[2 * w],     clo, yacc);
            s[2 * w + 1] = fmaf(s[2 * w + 1], dA, coef * bhi);
            yacc         = fmaf(s[2 * w + 1], chi, yacc);
        }
        yb[(size_t)t * DINNER] = yacc;    // plain store, 64 lanes coalesced
    }
}

// ------------- gated RMSNorm (yp0+yp1+xD)*silu(z), bf16 out ----------------
__global__ __launch_bounds__(256) void gated_rms_kernel(
    const float* __restrict__ yp0, const float* __restrict__ yp1,
    const float* __restrict__ convout, const float* __restrict__ zx,
    const float* __restrict__ Dv, const float* __restrict__ norm_w,
    u16* __restrict__ gout)
{
    int bl = blockIdx.x;
    int c = threadIdx.x * 4;
    float4 y0 = *reinterpret_cast<const float4*>(yp0 + (size_t)bl * DINNER + c);
    float4 y1 = *reinterpret_cast<const float4*>(yp1 + (size_t)bl * DINNER + c);
    float4 xv = *reinterpret_cast<const float4*>(convout + (size_t)bl * CONVDIM + c);
    float4 zv = *reinterpret_cast<const float4*>(zx + (size_t)bl * NPROJ_PAD + c);
    float Dh = Dv[c >> 6];
    float g0 = (y0.x + y1.x + xv.x * Dh) * silu_f(zv.x);
    float g1 = (y0.y + y1.y + xv.y * Dh) * silu_f(zv.y);
    float g2 = (y0.z + y1.z + xv.z * Dh) * silu_f(zv.z);
    float g3 = (y0.w + y1.w + xv.w * Dh) * silu_f(zv.w);
    float tot = block_sum(g0 * g0 + g1 * g1 + g2 * g2 + g3 * g3);
    float sc = rsqrtf(tot * (1.f / DINNER) + 1e-5f);
    float4 nw = *reinterpret_cast<const float4*>(norm_w + c);
    ushort4 o;
    o.x = f2bf(g0 * sc * nw.x); o.y = f2bf(g1 * sc * nw.y);
    o.z = f2bf(g2 * sc * nw.z); o.w = f2bf(g3 * sc * nw.w);
    *reinterpret_cast<ushort4*>(gout + (size_t)bl * DINNER + c) = o;
}

// ---- residual + 4 split-K partials + RMSNorm (no weight), f32 out ---------
// blockDim = ncols/4; partial s at pbuf + s*rows*ncols
__global__ void residual_rms_sk_kernel(
    const float* __restrict__ a, const float* __restrict__ pbuf,
    float* __restrict__ outf, int ncols, int rows)
{
    int row = blockIdx.x;
    int c = threadIdx.x * 4;
    size_t slice = (size_t)rows * ncols;
    size_t off = (size_t)row * ncols + c;
    float4 va = *reinterpret_cast<const float4*>(a + off);
    float4 p0 = *reinterpret_cast<const float4*>(pbuf + off);
    float4 p1 = *reinterpret_cast<const float4*>(pbuf + slice + off);
    float4 p2 = *reinterpret_cast<const float4*>(pbuf + 2 * slice + off);
    float4 p3 = *reinterpret_cast<const float4*>(pbuf + 3 * slice + off);
    float v0 = va.x + ((p0.x + p1.x) + (p2.x + p3.x));
    float v1 = va.y + ((p0.y + p1.y) + (p2.y + p3.y));
    float v2 = va.z + ((p0.z + p1.z) + (p2.z + p3.z));
    float v3 = va.w + ((p0.w + p1.w) + (p2.w + p3.w));
    float tot = block_sum(v0 * v0 + v1 * v1 + v2 * v2 + v3 * v3);
    float sc = rsqrtf(tot / (float)ncols + 1e-5f);
    float4 o; o.x = v0 * sc; o.y = v1 * sc; o.z = v2 * sc; o.w = v3 * sc;
    *reinterpret_cast<float4*>(outf + off) = o;
}

// ------------- transpose per batch: in (R,C) -> out (C,R), dual write ------
__global__ __launch_bounds__(256) void transpose_dual_kernel(
    const float* __restrict__ in, u16* __restrict__ outb,
    float* __restrict__ outf, int R, int C)
{
    __shared__ float tile[32][33];
    int b = blockIdx.z;
    int c0 = blockIdx.x * 32, r0 = blockIdx.y * 32;
    const float* ip = in + (size_t)b * R * C;
    for (int i = threadIdx.y; i < 32; i += 8)
        tile[i][threadIdx.x] = ip[(size_t)(r0 + i) * C + c0 + threadIdx.x];
    __syncthreads();
    size_t ob = (size_t)b * R * C;
    for (int i = threadIdx.y; i < 32; i += 8) {
        float v = tile[threadIdx.x][i];
        size_t oi = ob + (size_t)(c0 + i) * R + r0 + threadIdx.x;
        outf[oi] = v;
        outb[oi] = f2bf(v);
    }
}

// ------------------------------ SwiGLU -------------------------------------
__global__ __launch_bounds__(256) void swiglu_kernel(
    const float* __restrict__ t, u16* __restrict__ act, int rows, int inter)
{
    int idx = blockIdx.x * 256 + threadIdx.x;
    if (idx >= rows * inter) return;
    int r = idx / inter, c = idx - r * inter;
    float g = t[(size_t)r * 2 * inter + c];
    float u = t[(size_t)r * 2 * inter + inter + c];
    act[idx] = f2bf(silu_f(g) * u);
}

// ---------------------------------------------------------------------------
extern "C" void kernel_launch(void* const* d_in, const int* in_sizes, int n_in,
                              void* d_out, int out_size, void* d_ws, size_t ws_size,
                              hipStream_t stream)
{
    const float* hid      = (const float*)d_in[0];
    const float* in_proj  = (const float*)d_in[1];
    const float* conv_w   = (const float*)d_in[2];
    const float* conv_b   = (const float*)d_in[3];
    const float* dt_bias  = (const float*)d_in[4];
    const float* A_log    = (const float*)d_in[5];
    const float* Dv       = (const float*)d_in[6];
    const float* norm_w   = (const float*)d_in[7];
    const float* out_proj = (const float*)d_in[8];
    const float* gu_t     = (const float*)d_in[9];
    const float* down_t   = (const float*)d_in[10];
    const float* gu_m     = (const float*)d_in[11];
    const float* down_m   = (const float*)d_in[12];
    float* outp = (float*)d_out;

    char* ws = (char*)d_ws;
    u16* bf        = (u16*)ws;
    u16* hid_bf    = bf;
    u16* w_inproj  = bf + HID_E;
    u16* w_outproj = w_inproj + INPROJ_P_E;
    u16* w_gut     = w_outproj + OUTPROJ_E;
    u16* w_downt   = w_gut + GUT_E;
    u16* w_gum     = w_downt + DOWNT_E;
    u16* w_downm   = w_gum + GUM_E;
    size_t o = (size_t)(CONV_TOT_E * 2);
    auto alloc = [&](size_t bytes) { size_t r = o; o = (o + bytes + 255) & ~(size_t)255; return r; };
    size_t dt_off  = alloc(4096 * 16 * 4);
    size_t g_off   = alloc((size_t)4096 * 1024 * 2);
    size_t h1_off  = alloc((size_t)4096 * 512 * 4);
    size_t Pt_off  = alloc(2048 * 4);
    // ---- MLP region (live step 8+); Sc/Sinit OVERLAY it (live steps 4-5).
    // Region must hold Sc+Sinit = 2 x 8192*1024*4 = 67,108,864 B.
    // Sum below (xtb..act2) = 57,671,680 B -> pad 10 MB => 68,157,440 B. OK.
    size_t xtb_off = alloc((size_t)2048 * 1024 * 2);
    size_t xtf_off = alloc((size_t)2048 * 1024 * 4);
    size_t act1_off= alloc((size_t)2048 * 2816 * 2);
    size_t x2_off  = alloc((size_t)2048 * 1024 * 4);
    size_t h2b_off = alloc((size_t)4096 * 512 * 2);
    size_t h2f_off = alloc((size_t)4096 * 512 * 4);
    size_t act2_off= alloc((size_t)4096 * 1536 * 2);
    size_t pad_off = alloc((size_t)10 * 1024 * 1024);
    size_t Sc_off  = xtb_off;                          // 33.55 MB
    size_t Si_off  = xtb_off + (size_t)8192 * 1024 * 4;// 33.55 MB
    (void)pad_off;
    // overlay region R_off: {zxbcdt, convout, yp0} live until gated_rms;
    // then split-K partials (33.5 MB) / t1 (46 MB) / t3 (50 MB) time-share it.
    size_t R_off   = o;
    size_t zx_off  = R_off;
    size_t cv_off  = zx_off + (size_t)4096 * NPROJ_PAD * 4;
    size_t y_off   = cv_off + (size_t)4096 * CONVDIM * 4;
    size_t t1_off  = R_off;
    size_t t3_off  = R_off;
    size_t sk_off  = R_off;

    float* zx      = (float*)(ws + zx_off);
    float* convout = (float*)(ws + cv_off);
    float* ybuf    = (float*)(ws + y_off);           // yp0
    float* dtbuf   = (float*)(ws + dt_off);
    u16*   g_bf    = (u16*)(ws + g_off);
    float* h1      = (float*)(ws + h1_off);
    u16*   xt_bf   = (u16*)(ws + xtb_off);
    float* xt_f    = (float*)(ws + xtf_off);
    float* t1      = (float*)(ws + t1_off);
    u16*   act1    = (u16*)(ws + act1_off);
    float* x2      = (float*)(ws + x2_off);
    u16*   h2_bf   = (u16*)(ws + h2b_off);
    float* h2_f    = (float*)(ws + h2f_off);
    float* t3      = (float*)(ws + t3_off);
    u16*   act2    = (u16*)(ws + act2_off);
    float* skbuf   = (float*)(ws + sk_off);          // split-K partials x4
    float* Sc      = (float*)(ws + Sc_off);          // yp1 after scan_combine
    float* Sinit   = (float*)(ws + Si_off);
    float* Ptot    = (float*)(ws + Pt_off);

    // 1) convert weights + hidden to bf16
    convert_all_kernel<<<14464, 256, 0, stream>>>(
        hid, in_proj, out_proj, gu_t, down_t, gu_m, down_m, bf);

    // 2) zxbcdt = hidden @ in_proj^T  (576 blocks)
    gemm_bt<<<dim3(NPROJ_PAD / 128, 4096 / 128), 256, 0, stream>>>(
        hid_bf, w_inproj, zx, 4096, NPROJ_PAD, 512);

    // 3) conv + dt
    conv_dt_kernel<<<18688, 256, 0, stream>>>(zx, conv_w, conv_b, dt_bias, convout, dtbuf);

    // 4) chunked SSM scan (CHUNK=32; phase2 halves; yp0=ybuf, yp1=Sc reuse)
    scan_phase1<<<2048, 256, 0, stream>>>(convout, dtbuf, A_log, Sc, Ptot);
    scan_combine<<<256, 64, 0, stream>>>(Sc, Ptot, Sinit);
    scan_phase2<<<2048, 128, 0, stream>>>(convout, dtbuf, A_log, Sinit, ybuf, Sc);

    // 5) gated RMSNorm -> bf16  (zx/convout/ybuf dead after this)
    gated_rms_kernel<<<4096, 256, 0, stream>>>(ybuf, Sc, convout, zx, Dv, norm_w, g_bf);

    // 6) out_proj GEMM, split-K x4 -> partials in skbuf (512 blocks)
    gemm_bt_sk<<<dim3(512 / 128, 4096 / 128, 4), 256, 0, stream>>>(
        g_bf, w_outproj, skbuf, 4096, 512, 1024, 256);

    // 7) h1 = rms(hidden + sum partials)
    residual_rms_sk_kernel<<<4096, 128, 0, stream>>>(hid, skbuf, h1, 512, 4096);

    // 8) transpose (B,1024,512) -> (B,512,1024)  [overwrites Sc region - dead]
    transpose_dual_kernel<<<dim3(16, 32, 4), dim3(32, 8), 0, stream>>>(h1, xt_bf, xt_f, 1024, 512);

    // 9) token MLP: t1 = xt @ gu_t^T (704 blocks)  [t1 overwrites skbuf - dead]
    gemm_bt<<<dim3(5632 / 128, 2048 / 128), 256, 0, stream>>>(xt_bf, w_gut, t1, 2048, 5632, 1024);

    // 10) swiglu -> act1 bf16
    swiglu_kernel<<<22528, 256, 0, stream>>>(t1, act1, 2048, 2816);

    // 11) down_t GEMM, split-K x4 -> partials in skbuf (512 blocks) [t1 dead]
    gemm_bt_sk<<<dim3(1024 / 128, 2048 / 128, 4), 256, 0, stream>>>(
        act1, w_downt, skbuf, 2048, 1024, 2816, 704);

    // 12) x2 = rms(xt_f + sum partials)
    residual_rms_sk_kernel<<<2048, 256, 0, stream>>>(xt_f, skbuf, x2, 1024, 2048);

    // 13) transpose back (B,512,1024) -> (B,1024,512)
    transpose_dual_kernel<<<dim3(32, 16, 4), dim3(32, 8), 0, stream>>>(x2, h2_bf, h2_f, 512, 1024);

    // 14) channel MLP: t3 = h2 @ gu_m^T (768 blocks) [t3 overwrites skbuf - dead]
    gemm_bt<<<dim3(3072 / 128, 4096 / 128), 256, 0, stream>>>(h2_bf, w_gum, t3, 4096, 3072, 512);

    // 15) swiglu -> act2 bf16
    swiglu_kernel<<<24576, 256, 0, stream>>>(t3, act2, 4096, 1536);

    // 16) down_m GEMM, split-K x4 -> partials in skbuf (512 blocks) [t3 dead]
    gemm_bt_sk<<<dim3(512 / 128, 4096 / 128, 4), 256, 0, stream>>>(
        act2, w_downm, skbuf, 4096, 512, 1536, 384);

    // 17) out = rms(h2_f + sum partials)
    residual_rms_sk_kernel<<<4096, 128, 0, stream>>>(h2_f, skbuf, outp, 512, 4096);
}

// Round 11
// 439.694 us; speedup vs baseline: 1.0009x; 1.0009x over previous
//
#include <hip/hip_runtime.h>

// ---------------------------------------------------------------------------
// Mamba2 hybrid block. GEMMs: bf16 MFMA 16x16x32, f32 accumulate, m97-style
// global_load_lds(16B) staging with XOR bank swizzle. Small-N GEMMs use
// split-K x4 into SEPARATE partial buffers (plain stores, no atomics);
// partials summed inside the downstream residual_rms kernel. Scan: 3-phase
// chunked, CHUNK=32; B/C staged in LDS as BF16. R10 lesson: phase2's serial
// 32-deep yacc FMA chain was the stall (VALUBusy 55%, no pipe saturated) —
// phase3 now splits y into 4 independent accumulators + separate state loop.
// ---------------------------------------------------------------------------

#define BB 4
#define LL 1024
#define DMODEL 512
#define DINNER 1024
#define NHEADS 16
#define HEADDIM 64
#define DSTATE 64
#define CONVDIM 1152        // DINNER + 2*DSTATE
#define NPROJ 2192          // D_IN_PROJ
#define NPROJ_PAD 2304      // padded to multiple of 128
#define INTER_T 2816
#define INTER_M 1536
#define NCHUNK 32
#define CHUNK 32

typedef __bf16 bf16x8 __attribute__((ext_vector_type(8)));
typedef float  f32x4  __attribute__((ext_vector_type(4)));
typedef unsigned short u16;
typedef unsigned int   u32;

__device__ __forceinline__ u16 f2bf(float x) {
    union { float f; u32 u; } v; v.f = x;
    u32 u = v.u;
    return (u16)((u + 0x7fffu + ((u >> 16) & 1u)) >> 16);
}
__device__ __forceinline__ float silu_f(float x) {
    return x / (1.f + __expf(-x));
}
// unpack 2 bf16 from one u32 word (little-endian: low half = even element)
__device__ __forceinline__ void bf2f2(u32 w, float& lo, float& hi) {
    union { u32 u; float f; } a, b;
    a.u = w << 16; b.u = w & 0xffff0000u;
    lo = a.f; hi = b.f;
}

// async global->LDS, 16B per lane; LDS dest is wave-uniform base + lane*16
__device__ __forceinline__ void gld_lds16(const u16* g, u16* l) {
    __builtin_amdgcn_global_load_lds(
        (const __attribute__((address_space(1))) unsigned int*)g,
        (__attribute__((address_space(3))) unsigned int*)l, 16, 0, 0);
}

// --------------------------- block-wide sum --------------------------------
__device__ __forceinline__ float block_sum(float v) {
    #pragma unroll
    for (int off = 32; off > 0; off >>= 1) v += __shfl_xor(v, off, 64);
    __shared__ float red[4];
    int w = threadIdx.x >> 6;
    int nwv = blockDim.x >> 6;
    if ((threadIdx.x & 63) == 0) red[w] = v;
    __syncthreads();
    float tot = red[0];
    for (int i = 1; i < nwv; i++) tot += red[i];
    return tot;
}

// --------------------- f32 -> bf16 convert (all weights + hidden) ----------
#define HID_E      2097152LL   // 4096*512
#define INPROJ_P_E 1179648LL   // 2304*512
#define INPROJ_S_E 1122304LL   // 2192*512
#define OUTPROJ_E   524288LL   // 512*1024
#define GUT_E      5767168LL   // 5632*1024
#define DOWNT_E    2883584LL   // 1024*2816
#define GUM_E      1572864LL   // 3072*512
#define DOWNM_E     786432LL   // 512*1536
#define CONV_TOT_E 14811136LL

__global__ __launch_bounds__(256) void convert_all_kernel(
    const float* __restrict__ s_hid, const float* __restrict__ s_inproj,
    const float* __restrict__ s_outproj, const float* __restrict__ s_gut,
    const float* __restrict__ s_downt, const float* __restrict__ s_gum,
    const float* __restrict__ s_downm, u16* __restrict__ dst)
{
    long long idx = (long long)blockIdx.x * 256 + threadIdx.x;
    long long e = idx * 4;
    if (e >= CONV_TOT_E) return;
    const float* src; long long off, nsrc;
    long long c0 = HID_E;
    long long c1 = c0 + INPROJ_P_E;
    long long c2 = c1 + OUTPROJ_E;
    long long c3 = c2 + GUT_E;
    long long c4 = c3 + DOWNT_E;
    long long c5 = c4 + GUM_E;
    if      (e < c0) { src = s_hid;     off = e;      nsrc = HID_E; }
    else if (e < c1) { src = s_inproj;  off = e - c0; nsrc = INPROJ_S_E; }
    else if (e < c2) { src = s_outproj; off = e - c1; nsrc = OUTPROJ_E; }
    else if (e < c3) { src = s_gut;     off = e - c2; nsrc = GUT_E; }
    else if (e < c4) { src = s_downt;   off = e - c3; nsrc = DOWNT_E; }
    else if (e < c5) { src = s_gum;     off = e - c4; nsrc = GUM_E; }
    else             { src = s_downm;   off = e - c5; nsrc = DOWNM_E; }
    ushort4 r;
    if (off < nsrc) {
        float4 v = *reinterpret_cast<const float4*>(src + off);
        r.x = f2bf(v.x); r.y = f2bf(v.y); r.z = f2bf(v.z); r.w = f2bf(v.w);
    } else {
        r.x = 0; r.y = 0; r.z = 0; r.w = 0;
    }
    *reinterpret_cast<ushort4*>(dst + e) = r;
}

// ----------------------------- bf16 MFMA GEMM ------------------------------
// C[M,N] = A[M,K] * W[N,K]^T. 128x128 tile, 4 waves of 64x64 (4x4 MFMAs).
// global_load_lds staging (no pad; XOR chunk swizzle vs bank conflicts).
// SK: write this slice's tile to C + slice*M*N (plain stores; summed later).
template<bool SK>
__device__ __forceinline__ void gemm_bt_body(
    const u16* __restrict__ A, const u16* __restrict__ W,
    float* __restrict__ C, int M, int N, int K, int kLen)
{
    __shared__ u16 As[128 * 32];
    __shared__ u16 Bs[128 * 32];
    int tid = threadIdx.x;
    int m0 = blockIdx.y * 128, n0 = blockIdx.x * 128;
    int kBase = SK ? blockIdx.z * kLen : 0;
    float* Cw = SK ? C + (size_t)blockIdx.z * M * N : C;
    int wave = tid >> 6, lane = tid & 63;
    int wm = (wave >> 1) * 64, wn = (wave & 1) * 64;
    int lrow = lane & 15;
    int kq = lane >> 4;
    int kx = (lrow & 3) ^ ((lrow >> 2) & 3);
    int ko = (kq ^ kx) * 8;           // swizzled LDS chunk offset for frags

    int rL = lane >> 2, cL = lane & 3;
    int cG = cL ^ ((rL & 3) ^ ((rL >> 2) & 3));
    int R0 = wave * 32 + rL;
    int R1 = R0 + 16;
    const u16* gA0 = A + (size_t)(m0 + R0) * K + kBase + cG * 8;
    const u16* gA1 = A + (size_t)(m0 + R1) * K + kBase + cG * 8;
    const u16* gB0 = W + (size_t)(n0 + R0) * K + kBase + cG * 8;
    const u16* gB1 = W + (size_t)(n0 + R1) * K + kBase + cG * 8;
    u16* lA0 = &As[(wave * 32) * 32];
    u16* lA1 = &As[(wave * 32 + 16) * 32];
    u16* lB0 = &Bs[(wave * 32) * 32];
    u16* lB1 = &Bs[(wave * 32 + 16) * 32];

    f32x4 acc[4][4];
    #pragma unroll
    for (int i = 0; i < 4; i++)
        #pragma unroll
        for (int j = 0; j < 4; j++) {
            acc[i][j][0] = 0.f; acc[i][j][1] = 0.f;
            acc[i][j][2] = 0.f; acc[i][j][3] = 0.f;
        }

    for (int kt = 0; kt < kLen; kt += 32) {
        __syncthreads();
        gld_lds16(gA0 + kt, lA0);
        gld_lds16(gA1 + kt, lA1);
        gld_lds16(gB0 + kt, lB0);
        gld_lds16(gB1 + kt, lB1);
        __syncthreads();
        bf16x8 af[4], bfr[4];
        #pragma unroll
        for (int i = 0; i < 4; i++) {
            af[i]  = *reinterpret_cast<const bf16x8*>(&As[(wm + i * 16 + lrow) * 32 + ko]);
            bfr[i] = *reinterpret_cast<const bf16x8*>(&Bs[(wn + i * 16 + lrow) * 32 + ko]);
        }
        #pragma unroll
        for (int i = 0; i < 4; i++)
            #pragma unroll
            for (int j = 0; j < 4; j++)
                acc[i][j] = __builtin_amdgcn_mfma_f32_16x16x32_bf16(af[i], bfr[j], acc[i][j], 0, 0, 0);
    }

    // C/D layout: col = lane&15, row = (lane>>4)*4 + reg
    int rbase = m0 + wm + kq * 4;
    int cbase = n0 + wn + lrow;
    #pragma unroll
    for (int i = 0; i < 4; i++)
        #pragma unroll
        for (int j = 0; j < 4; j++)
            #pragma unroll
            for (int r = 0; r < 4; r++)
                Cw[(size_t)(rbase + i * 16 + r) * N + cbase + j * 16] = acc[i][j][r];
}

__global__ __launch_bounds__(256) void gemm_bt(
    const u16* __restrict__ A, const u16* __restrict__ W,
    float* __restrict__ C, int M, int N, int K)
{
    gemm_bt_body<false>(A, W, C, M, N, K, K);
}

__global__ __launch_bounds__(256) void gemm_bt_sk(
    const u16* __restrict__ A, const u16* __restrict__ W,
    float* __restrict__ C, int M, int N, int K, int kLen)
{
    gemm_bt_body<true>(A, W, C, M, N, K, kLen);
}

// ----------------- conv (depthwise, causal, width 4) + dt ------------------
__global__ __launch_bounds__(256) void conv_dt_kernel(
    const float* __restrict__ zx, const float* __restrict__ conv_w,
    const float* __restrict__ conv_b, const float* __restrict__ dt_bias,
    float* __restrict__ convout, float* __restrict__ dtbuf)
{
    int idx = blockIdx.x * 256 + threadIdx.x;   // over 4096*1168
    int bl = idx / 1168;
    int c  = idx - bl * 1168;
    int l  = bl & (LL - 1);
    if (c < CONVDIM) {
        const float* col = zx + (size_t)bl * NPROJ_PAD + DINNER + c;
        float acc = conv_b[c];
        #pragma unroll
        for (int i = 0; i < 4; i++) {
            int lt = l - 3 + i;
            float v = (lt >= 0) ? col[(long long)(lt - l) * NPROJ_PAD] : 0.f;
            acc = fmaf(v, conv_w[c * 4 + i], acc);
        }
        convout[(size_t)bl * CONVDIM + c] = silu_f(acc);
    } else {
        int h = c - CONVDIM;
        float v = zx[(size_t)bl * NPROJ_PAD + 2176 + h] + dt_bias[h];
        float sp = (v > 20.f) ? v : log1pf(__expf(v));
        dtbuf[(size_t)bl * NHEADS + h] = sp;
    }
}

// ----------------------- chunked SSM scan: phase 1 -------------------------
// block = (b*16+h)*32 + c, 256 thr; wave = nq (16 states/lane); B (bf16) + dt
// staged in LDS once per chunk. 32 steps from zero state -> Sc, Ptot.
__global__ __launch_bounds__(256) void scan_phase1(
    const float* __restrict__ convout, const float* __restrict__ dtbuf,
    const float* __restrict__ A_log, float* __restrict__ Sc,
    float* __restrict__ Ptot)
{
    __shared__ u16 Blds[CHUNK * 64];     // 4 KB, bf16
    __shared__ float dtl[CHUNK];
    int blk = blockIdx.x;
    int c   = blk & 31;
    int bh  = blk >> 5;
    int b = bh >> 4, h = bh & 15;
    int nq = threadIdx.x >> 6;
    int p  = threadIdx.x & 63;
    size_t base = ((size_t)b * LL + (size_t)c * CHUNK) * CONVDIM;

    const float* Bsrc = convout + base + DINNER;
    #pragma unroll
    for (int i = threadIdx.x; i < CHUNK * 16; i += 256) {   // 512 float4s
        int t = i >> 4, q = i & 15;
        float4 v = *reinterpret_cast<const float4*>(&Bsrc[(size_t)t * CONVDIM + q * 4]);
        ushort4 r; r.x = f2bf(v.x); r.y = f2bf(v.y); r.z = f2bf(v.z); r.w = f2bf(v.w);
        *reinterpret_cast<ushort4*>(&Blds[t * 64 + q * 4]) = r;
    }
    const float* db = dtbuf + ((size_t)b * LL + (size_t)c * CHUNK) * NHEADS + h;
    if (threadIdx.x < CHUNK) dtl[threadIdx.x] = db[(size_t)threadIdx.x * NHEADS];
    __syncthreads();

    float Ah = -__expf(A_log[h]);
    const float* xb = convout + base + h * HEADDIM + p;

    float s[16];
    #pragma unroll
    for (int j = 0; j < 16; j++) s[j] = 0.f;
    float dtsum = 0.f;

    float xvc = xb[0];
    for (int t = 0; t < CHUNK; ++t) {
        float dt = dtl[t];
        float xv = xvc;
        int tn = (t < CHUNK - 1) ? t + 1 : CHUNK - 1;
        xvc = xb[(size_t)tn * CONVDIM];
        const uint4* Bp = reinterpret_cast<const uint4*>(&Blds[t * 64 + nq * 16]);
        uint4 b0 = Bp[0], b1 = Bp[1];
        u32 Bw[8] = { b0.x, b0.y, b0.z, b0.w, b1.x, b1.y, b1.z, b1.w };
        float dA = __expf(dt * Ah);
        dtsum += dt;
        float coef = dt * xv;
        #pragma unroll
        for (int w = 0; w < 8; w++) {
            float lo, hi; bf2f2(Bw[w], lo, hi);
            s[2 * w]     = fmaf(s[2 * w],     dA, coef * lo);
            s[2 * w + 1] = fmaf(s[2 * w + 1], dA, coef * hi);
        }
    }
    float* So = Sc + ((size_t)(bh * 4 + nq) * NCHUNK + c) * 1024 + p * 16;
    #pragma unroll
    for (int q = 0; q < 4; q++) {
        float4 v; v.x = s[q*4]; v.y = s[q*4+1]; v.z = s[q*4+2]; v.w = s[q*4+3];
        *reinterpret_cast<float4*>(So + q * 4) = v;
    }
    if (nq == 0 && p == 0) Ptot[bh * NCHUNK + c] = __expf(Ah * dtsum);
}

// ----------------------- chunked SSM scan: phase 2 -------------------------
// block = (b*16+h)*4 + nq (256 blocks); sequential carry over 32 chunks.
__global__ __launch_bounds__(64) void scan_combine(
    const float* __restrict__ Sc, const float* __restrict__ Ptot,
    float* __restrict__ Sinit)
{
    int blk = blockIdx.x;
    int bh = blk >> 2;
    int p = threadIdx.x;
    float carry[16];
    #pragma unroll
    for (int j = 0; j < 16; j++) carry[j] = 0.f;
    for (int c = 0; c < NCHUNK; ++c) {
        size_t row = ((size_t)blk * NCHUNK + c) * 1024 + p * 16;
        float* o = Sinit + row;
        #pragma unroll
        for (int j = 0; j < 16; j++) o[j] = carry[j];
        float P = Ptot[bh * NCHUNK + c];
        const float* si = Sc + row;
        #pragma unroll
        for (int j = 0; j < 16; j++) carry[j] = fmaf(carry[j], P, si[j]);
    }
}

// ----------------------- chunked SSM scan: phase 3 -------------------------
// block = (b*16+h)*32 + c, 128 thr; wave = nh (32 states/lane). B+C (bf16)
// + dt staged in LDS; per step: 8 b128 broadcast reads + in-reg bf16 unpack.
// State updates (independent) and y-reduction (4 parallel accumulator
// chains, depth 8) are SEPARATE loops to expose ILP — R10's interleaved
// 32-deep yacc chain was the stall. y per-lane complete -> plain stores.
__global__ __launch_bounds__(128) void scan_phase2(
    const float* __restrict__ convout, const float* __restrict__ dtbuf,
    const float* __restrict__ A_log, const float* __restrict__ Sinit,
    float* __restrict__ yp0, float* __restrict__ yp1)
{
    __shared__ u16 BClds[CHUNK * 128];   // 8 KB, bf16 (B 64 | C 64 per step)
    __shared__ float dtl[CHUNK];
    int blk = blockIdx.x;
    int c   = blk & 31;
    int bh  = blk >> 5;
    int b = bh >> 4, h = bh & 15;
    int nh = threadIdx.x >> 6;
    int p  = threadIdx.x & 63;
    size_t base = ((size_t)b * LL + (size_t)c * CHUNK) * CONVDIM;

    const float* BCsrc = convout + base + DINNER;
    #pragma unroll
    for (int i = threadIdx.x; i < CHUNK * 32; i += 128) {   // 1024 float4s
        int t = i >> 5, q = i & 31;
        float4 v = *reinterpret_cast<const float4*>(&BCsrc[(size_t)t * CONVDIM + q * 4]);
        ushort4 r; r.x = f2bf(v.x); r.y = f2bf(v.y); r.z = f2bf(v.z); r.w = f2bf(v.w);
        *reinterpret_cast<ushort4*>(&BClds[t * 128 + q * 4]) = r;
    }
    const float* db = dtbuf + ((size_t)b * LL + (size_t)c * CHUNK) * NHEADS + h;
    if (threadIdx.x < CHUNK) dtl[threadIdx.x] = db[(size_t)threadIdx.x * NHEADS];
    __syncthreads();

    float Ah = -__expf(A_log[h]);
    const float* xb = convout + base + h * HEADDIM + p;
    float* yb = (nh ? yp1 : yp0)
              + ((size_t)b * LL + (size_t)c * CHUNK) * DINNER + h * HEADDIM + p;

    float s[32];
    {   // states j<16 from quarter 2*nh, j>=16 from quarter 2*nh+1
        const float* si0 = Sinit + ((size_t)(bh * 4 + nh * 2)     * NCHUNK + c) * 1024 + p * 16;
        const float* si1 = Sinit + ((size_t)(bh * 4 + nh * 2 + 1) * NCHUNK + c) * 1024 + p * 16;
        #pragma unroll
        for (int j = 0; j < 16; j++) { s[j] = si0[j]; s[16 + j] = si1[j]; }
    }

    float xvc = xb[0];
    for (int t = 0; t < CHUNK; ++t) {
        float dt = dtl[t];
        float xv = xvc;
        int tn = (t < CHUNK - 1) ? t + 1 : CHUNK - 1;
        xvc = xb[(size_t)tn * CONVDIM];
        const uint4* Bp = reinterpret_cast<const uint4*>(&BClds[t * 128 + nh * 32]);
        const uint4* Cp = reinterpret_cast<const uint4*>(&BClds[t * 128 + 64 + nh * 32]);
        uint4 b0 = Bp[0], b1 = Bp[1], b2 = Bp[2], b3 = Bp[3];
        uint4 c0 = Cp[0], c1 = Cp[1], c2 = Cp[2], c3 = Cp[3];
        u32 Bw[16] = { b0.x,b0.y,b0.z,b0.w, b1.x,b1.y,b1.z,b1.w,
                       b2.x,b2.y,b2.z,b2.w, b3.x,b3.y,b3.z,b3.w };
        u32 Cw[16] = { c0.x,c0.y,c0.z,c0.w, c1.x,c1.y,c1.z,c1.w,
                       c2.x,c2.y,c2.z,c2.w, c3.x,c3.y,c3.z,c3.w };
        float dA = __expf(dt * Ah);
        float coef = dt * xv;
        // state updates: 32 independent 2-op chains
        #pragma unroll
        for (int w = 0; w < 16; w++) {
            float blo, bhi; bf2f2(Bw[w], blo, bhi);
            s[2 * w]     = fmaf(s[2 * w],     dA, coef * blo);
            s[2 * w + 1] = fmaf(s[2 * w + 1], dA, coef * bhi);
        }
        // y-reduction: 4 independent accumulator chains (depth 8)
        float y0 = 0.f, y1 = 0.f, y2 = 0.f, y3 = 0.f;
        #pragma unroll
        for (int w = 0; w < 16; w += 2) {
            float cl0, ch0, cl1, ch1;
            bf2f2(Cw[w],     cl0, ch0);
            bf2f2(Cw[w + 1], cl1, ch1);
            y0 = fmaf(s[2 * w],     cl0, y0);
            y1 = fmaf(s[2 * w + 1], ch0, y1);
            y2 = fmaf(s[2 * w + 2], cl1, y2);
            y3 = fmaf(s[2 * w + 3], ch1, y3);
        }
        yb[(size_t)t * DINNER] = (y0 + y1) + (y2 + y3);
    }
}

// ------------- gated RMSNorm (yp0+yp1+xD)*silu(z), bf16 out ----------------
__global__ __launch_bounds__(256) void gated_rms_kernel(
    const float* __restrict__ yp0, const float* __restrict__ yp1,
    const float* __restrict__ convout, const float* __restrict__ zx,
    const float* __restrict__ Dv, const float* __restrict__ norm_w,
    u16* __restrict__ gout)
{
    int bl = blockIdx.x;
    int c = threadIdx.x * 4;
    float4 y0 = *reinterpret_cast<const float4*>(yp0 + (size_t)bl * DINNER + c);
    float4 y1 = *reinterpret_cast<const float4*>(yp1 + (size_t)bl * DINNER + c);
    float4 xv = *reinterpret_cast<const float4*>(convout + (size_t)bl * CONVDIM + c);
    float4 zv = *reinterpret_cast<const float4*>(zx + (size_t)bl * NPROJ_PAD + c);
    float Dh = Dv[c >> 6];
    float g0 = (y0.x + y1.x + xv.x * Dh) * silu_f(zv.x);
    float g1 = (y0.y + y1.y + xv.y * Dh) * silu_f(zv.y);
    float g2 = (y0.z + y1.z + xv.z * Dh) * silu_f(zv.z);
    float g3 = (y0.w + y1.w + xv.w * Dh) * silu_f(zv.w);
    float tot = block_sum(g0 * g0 + g1 * g1 + g2 * g2 + g3 * g3);
    float sc = rsqrtf(tot * (1.f / DINNER) + 1e-5f);
    float4 nw = *reinterpret_cast<const float4*>(norm_w + c);
    ushort4 o;
    o.x = f2bf(g0 * sc * nw.x); o.y = f2bf(g1 * sc * nw.y);
    o.z = f2bf(g2 * sc * nw.z); o.w = f2bf(g3 * sc * nw.w);
    *reinterpret_cast<ushort4*>(gout + (size_t)bl * DINNER + c) = o;
}

// ---- residual + 4 split-K partials + RMSNorm (no weight), f32 out ---------
// blockDim = ncols/4; partial s at pbuf + s*rows*ncols
__global__ void residual_rms_sk_kernel(
    const float* __restrict__ a, const float* __restrict__ pbuf,
    float* __restrict__ outf, int ncols, int rows)
{
    int row = blockIdx.x;
    int c = threadIdx.x * 4;
    size_t slice = (size_t)rows * ncols;
    size_t off = (size_t)row * ncols + c;
    float4 va = *reinterpret_cast<const float4*>(a + off);
    float4 p0 = *reinterpret_cast<const float4*>(pbuf + off);
    float4 p1 = *reinterpret_cast<const float4*>(pbuf + slice + off);
    float4 p2 = *reinterpret_cast<const float4*>(pbuf + 2 * slice + off);
    float4 p3 = *reinterpret_cast<const float4*>(pbuf + 3 * slice + off);
    float v0 = va.x + ((p0.x + p1.x) + (p2.x + p3.x));
    float v1 = va.y + ((p0.y + p1.y) + (p2.y + p3.y));
    float v2 = va.z + ((p0.z + p1.z) + (p2.z + p3.z));
    float v3 = va.w + ((p0.w + p1.w) + (p2.w + p3.w));
    float tot = block_sum(v0 * v0 + v1 * v1 + v2 * v2 + v3 * v3);
    float sc = rsqrtf(tot / (float)ncols + 1e-5f);
    float4 o; o.x = v0 * sc; o.y = v1 * sc; o.z = v2 * sc; o.w = v3 * sc;
    *reinterpret_cast<float4*>(outf + off) = o;
}

// ------------- transpose per batch: in (R,C) -> out (C,R), dual write ------
__global__ __launch_bounds__(256) void transpose_dual_kernel(
    const float* __restrict__ in, u16* __restrict__ outb,
    float* __restrict__ outf, int R, int C)
{
    __shared__ float tile[32][33];
    int b = blockIdx.z;
    int c0 = blockIdx.x * 32, r0 = blockIdx.y * 32;
    const float* ip = in + (size_t)b * R * C;
    for (int i = threadIdx.y; i < 32; i += 8)
        tile[i][threadIdx.x] = ip[(size_t)(r0 + i) * C + c0 + threadIdx.x];
    __syncthreads();
    size_t ob = (size_t)b * R * C;
    for (int i = threadIdx.y; i < 32; i += 8) {
        float v = tile[threadIdx.x][i];
        size_t oi = ob + (size_t)(c0 + i) * R + r0 + threadIdx.x;
        outf[oi] = v;
        outb[oi] = f2bf(v);
    }
}

// ------------------------------ SwiGLU -------------------------------------
__global__ __launch_bounds__(256) void swiglu_kernel(
    const float* __restrict__ t, u16* __restrict__ act, int rows, int inter)
{
    int idx = blockIdx.x * 256 + threadIdx.x;
    if (idx >= rows * inter) return;
    int r = idx / inter, c = idx - r * inter;
    float g = t[(size_t)r * 2 * inter + c];
    float u = t[(size_t)r * 2 * inter + inter + c];
    act[idx] = f2bf(silu_f(g) * u);
}

// ---------------------------------------------------------------------------
extern "C" void kernel_launch(void* const* d_in, const int* in_sizes, int n_in,
                              void* d_out, int out_size, void* d_ws, size_t ws_size,
                              hipStream_t stream)
{
    const float* hid      = (const float*)d_in[0];
    const float* in_proj  = (const float*)d_in[1];
    const float* conv_w   = (const float*)d_in[2];
    const float* conv_b   = (const float*)d_in[3];
    const float* dt_bias  = (const float*)d_in[4];
    const float* A_log    = (const float*)d_in[5];
    const float* Dv       = (const float*)d_in[6];
    const float* norm_w   = (const float*)d_in[7];
    const float* out_proj = (const float*)d_in[8];
    const float* gu_t     = (const float*)d_in[9];
    const float* down_t   = (const float*)d_in[10];
    const float* gu_m     = (const float*)d_in[11];
    const float* down_m   = (const float*)d_in[12];
    float* outp = (float*)d_out;

    char* ws = (char*)d_ws;
    u16* bf        = (u16*)ws;
    u16* hid_bf    = bf;
    u16* w_inproj  = bf + HID_E;
    u16* w_outproj = w_inproj + INPROJ_P_E;
    u16* w_gut     = w_outproj + OUTPROJ_E;
    u16* w_downt   = w_gut + GUT_E;
    u16* w_gum     = w_downt + DOWNT_E;
    u16* w_downm   = w_gum + GUM_E;
    size_t o = (size_t)(CONV_TOT_E * 2);
    auto alloc = [&](size_t bytes) { size_t r = o; o = (o + bytes + 255) & ~(size_t)255; return r; };
    size_t dt_off  = alloc(4096 * 16 * 4);
    size_t g_off   = alloc((size_t)4096 * 1024 * 2);
    size_t h1_off  = alloc((size_t)4096 * 512 * 4);
    size_t Pt_off  = alloc(2048 * 4);
    // ---- MLP region (live step 8+); Sc/Sinit OVERLAY it (live steps 4-5).
    // Region must hold Sc+Sinit = 2 x 8192*1024*4 = 67,108,864 B.
    // Sum below (xtb..act2) = 57,671,680 B -> pad 10 MB => 68,157,440 B. OK.
    size_t xtb_off = alloc((size_t)2048 * 1024 * 2);
    size_t xtf_off = alloc((size_t)2048 * 1024 * 4);
    size_t act1_off= alloc((size_t)2048 * 2816 * 2);
    size_t x2_off  = alloc((size_t)2048 * 1024 * 4);
    size_t h2b_off = alloc((size_t)4096 * 512 * 2);
    size_t h2f_off = alloc((size_t)4096 * 512 * 4);
    size_t act2_off= alloc((size_t)4096 * 1536 * 2);
    size_t pad_off = alloc((size_t)10 * 1024 * 1024);
    size_t Sc_off  = xtb_off;                          // 33.55 MB
    size_t Si_off  = xtb_off + (size_t)8192 * 1024 * 4;// 33.55 MB
    (void)pad_off;
    // overlay region R_off: {zxbcdt, convout, yp0} live until gated_rms;
    // then split-K partials (33.5 MB) / t1 (46 MB) / t3 (50 MB) time-share it.
    size_t R_off   = o;
    size_t zx_off  = R_off;
    size_t cv_off  = zx_off + (size_t)4096 * NPROJ_PAD * 4;
    size_t y_off   = cv_off + (size_t)4096 * CONVDIM * 4;
    size_t t1_off  = R_off;
    size_t t3_off  = R_off;
    size_t sk_off  = R_off;

    float* zx      = (float*)(ws + zx_off);
    float* convout = (float*)(ws + cv_off);
    float* ybuf    = (float*)(ws + y_off);           // yp0
    float* dtbuf   = (float*)(ws + dt_off);
    u16*   g_bf    = (u16*)(ws + g_off);
    float* h1      = (float*)(ws + h1_off);
    u16*   xt_bf   = (u16*)(ws + xtb_off);
    float* xt_f    = (float*)(ws + xtf_off);
    float* t1      = (float*)(ws + t1_off);
    u16*   act1    = (u16*)(ws + act1_off);
    float* x2      = (float*)(ws + x2_off);
    u16*   h2_bf   = (u16*)(ws + h2b_off);
    float* h2_f    = (float*)(ws + h2f_off);
    float* t3      = (float*)(ws + t3_off);
    u16*   act2    = (u16*)(ws + act2_off);
    float* skbuf   = (float*)(ws + sk_off);          // split-K partials x4
    float* Sc      = (float*)(ws + Sc_off);          // yp1 after scan_combine
    float* Sinit   = (float*)(ws + Si_off);
    float* Ptot    = (float*)(ws + Pt_off);

    // 1) convert weights + hidden to bf16
    convert_all_kernel<<<14464, 256, 0, stream>>>(
        hid, in_proj, out_proj, gu_t, down_t, gu_m, down_m, bf);

    // 2) zxbcdt = hidden @ in_proj^T  (576 blocks)
    gemm_bt<<<dim3(NPROJ_PAD / 128, 4096 / 128), 256, 0, stream>>>(
        hid_bf, w_inproj, zx, 4096, NPROJ_PAD, 512);

    // 3) conv + dt
    conv_dt_kernel<<<18688, 256, 0, stream>>>(zx, conv_w, conv_b, dt_bias, convout, dtbuf);

    // 4) chunked SSM scan (CHUNK=32; phase2 halves; yp0=ybuf, yp1=Sc reuse)
    scan_phase1<<<2048, 256, 0, stream>>>(convout, dtbuf, A_log, Sc, Ptot);
    scan_combine<<<256, 64, 0, stream>>>(Sc, Ptot, Sinit);
    scan_phase2<<<2048, 128, 0, stream>>>(convout, dtbuf, A_log, Sinit, ybuf, Sc);

    // 5) gated RMSNorm -> bf16  (zx/convout/ybuf dead after this)
    gated_rms_kernel<<<4096, 256, 0, stream>>>(ybuf, Sc, convout, zx, Dv, norm_w, g_bf);

    // 6) out_proj GEMM, split-K x4 -> partials in skbuf (512 blocks)
    gemm_bt_sk<<<dim3(512 / 128, 4096 / 128, 4), 256, 0, stream>>>(
        g_bf, w_outproj, skbuf, 4096, 512, 1024, 256);

    // 7) h1 = rms(hidden + sum partials)
    residual_rms_sk_kernel<<<4096, 128, 0, stream>>>(hid, skbuf, h1, 512, 4096);

    // 8) transpose (B,1024,512) -> (B,512,1024)  [overwrites Sc region - dead]
    transpose_dual_kernel<<<dim3(16, 32, 4), dim3(32, 8), 0, stream>>>(h1, xt_bf, xt_f, 1024, 512);

    // 9) token MLP: t1 = xt @ gu_t^T (704 blocks)  [t1 overwrites skbuf - dead]
    gemm_bt<<<dim3(5632 / 128, 2048 / 128), 256, 0, stream>>>(xt_bf, w_gut, t1, 2048, 5632, 1024);

    // 10) swiglu -> act1 bf16
    swiglu_kernel<<<22528, 256, 0, stream>>>(t1, act1, 2048, 2816);

    // 11) down_t GEMM, split-K x4 -> partials in skbuf (512 blocks) [t1 dead]
    gemm_bt_sk<<<dim3(1024 / 128, 2048 / 128, 4), 256, 0, stream>>>(
        act1, w_downt, skbuf, 2048, 1024, 2816, 704);

    // 12) x2 = rms(xt_f + sum partials)
    residual_rms_sk_kernel<<<2048, 256, 0, stream>>>(xt_f, skbuf, x2, 1024, 2048);

    // 13) transpose back (B,512,1024) -> (B,1024,512)
    transpose_dual_kernel<<<dim3(32, 16, 4), dim3(32, 8), 0, stream>>>(x2, h2_bf, h2_f, 512, 1024);

    // 14) channel MLP: t3 = h2 @ gu_m^T (768 blocks) [t3 overwrites skbuf - dead]
    gemm_bt<<<dim3(3072 / 128, 4096 / 128), 256, 0, stream>>>(h2_bf, w_gum, t3, 4096, 3072, 512);

    // 15) swiglu -> act2 bf16
    swiglu_kernel<<<24576, 256, 0, stream>>>(t3, act2, 4096, 1536);

    // 16) down_m GEMM, split-K x4 -> partials in skbuf (512 blocks) [t3 dead]
    gemm_bt_sk<<<dim3(512 / 128, 4096 / 128, 4), 256, 0, stream>>>(
        act2, w_downm, skbuf, 4096, 512, 1536, 384);

    // 17) out = rms(h2_f + sum partials)
    residual_rms_sk_kernel<<<4096, 128, 0, stream>>>(h2_f, skbuf, outp, 512, 4096);
}

// Round 12
// 410.891 us; speedup vs baseline: 1.0711x; 1.0701x over previous
//
#include <hip/hip_runtime.h>

// ---------------------------------------------------------------------------
// Mamba2 hybrid block. GEMMs: bf16 MFMA 16x16x32, f32 accumulate, m97-style
// global_load_lds(16B) staging with XOR bank swizzle. Small-N GEMMs use
// split-K x4 into SEPARATE partial buffers (plain stores, no atomics);
// partials summed in the downstream residual_rms kernel. MLP gu-GEMMs fuse
// SwiGLU in the epilogue (gate+up tiles in one block; kills 96 MB of t1/t3
// intermediate traffic + 2 dispatches). Scan: 3-phase chunked, CHUNK=32,
// B/C in LDS as bf16 — FROZEN at ~50 µs (R10/R11: VALU-scan local plateau;
// further gains need MFMA chunk-scan reformulation).
// ---------------------------------------------------------------------------

#define BB 4
#define LL 1024
#define DMODEL 512
#define DINNER 1024
#define NHEADS 16
#define HEADDIM 64
#define DSTATE 64
#define CONVDIM 1152        // DINNER + 2*DSTATE
#define NPROJ 2192          // D_IN_PROJ
#define NPROJ_PAD 2304      // padded to multiple of 128
#define INTER_T 2816
#define INTER_M 1536
#define NCHUNK 32
#define CHUNK 32

typedef __bf16 bf16x8 __attribute__((ext_vector_type(8)));
typedef float  f32x4  __attribute__((ext_vector_type(4)));
typedef unsigned short u16;
typedef unsigned int   u32;

__device__ __forceinline__ u16 f2bf(float x) {
    union { float f; u32 u; } v; v.f = x;
    u32 u = v.u;
    return (u16)((u + 0x7fffu + ((u >> 16) & 1u)) >> 16);
}
__device__ __forceinline__ float silu_f(float x) {
    return x / (1.f + __expf(-x));
}
// unpack 2 bf16 from one u32 word (little-endian: low half = even element)
__device__ __forceinline__ void bf2f2(u32 w, float& lo, float& hi) {
    union { u32 u; float f; } a, b;
    a.u = w << 16; b.u = w & 0xffff0000u;
    lo = a.f; hi = b.f;
}

// async global->LDS, 16B per lane; LDS dest is wave-uniform base + lane*16
__device__ __forceinline__ void gld_lds16(const u16* g, u16* l) {
    __builtin_amdgcn_global_load_lds(
        (const __attribute__((address_space(1))) unsigned int*)g,
        (__attribute__((address_space(3))) unsigned int*)l, 16, 0, 0);
}

// --------------------------- block-wide sum --------------------------------
__device__ __forceinline__ float block_sum(float v) {
    #pragma unroll
    for (int off = 32; off > 0; off >>= 1) v += __shfl_xor(v, off, 64);
    __shared__ float red[4];
    int w = threadIdx.x >> 6;
    int nwv = blockDim.x >> 6;
    if ((threadIdx.x & 63) == 0) red[w] = v;
    __syncthreads();
    float tot = red[0];
    for (int i = 1; i < nwv; i++) tot += red[i];
    return tot;
}

// --------------------- f32 -> bf16 convert (all weights + hidden) ----------
#define HID_E      2097152LL   // 4096*512
#define INPROJ_P_E 1179648LL   // 2304*512
#define INPROJ_S_E 1122304LL   // 2192*512
#define OUTPROJ_E   524288LL   // 512*1024
#define GUT_E      5767168LL   // 5632*1024
#define DOWNT_E    2883584LL   // 1024*2816
#define GUM_E      1572864LL   // 3072*512
#define DOWNM_E     786432LL   // 512*1536
#define CONV_TOT_E 14811136LL

__global__ __launch_bounds__(256) void convert_all_kernel(
    const float* __restrict__ s_hid, const float* __restrict__ s_inproj,
    const float* __restrict__ s_outproj, const float* __restrict__ s_gut,
    const float* __restrict__ s_downt, const float* __restrict__ s_gum,
    const float* __restrict__ s_downm, u16* __restrict__ dst)
{
    long long idx = (long long)blockIdx.x * 256 + threadIdx.x;
    long long e = idx * 4;
    if (e >= CONV_TOT_E) return;
    const float* src; long long off, nsrc;
    long long c0 = HID_E;
    long long c1 = c0 + INPROJ_P_E;
    long long c2 = c1 + OUTPROJ_E;
    long long c3 = c2 + GUT_E;
    long long c4 = c3 + DOWNT_E;
    long long c5 = c4 + GUM_E;
    if      (e < c0) { src = s_hid;     off = e;      nsrc = HID_E; }
    else if (e < c1) { src = s_inproj;  off = e - c0; nsrc = INPROJ_S_E; }
    else if (e < c2) { src = s_outproj; off = e - c1; nsrc = OUTPROJ_E; }
    else if (e < c3) { src = s_gut;     off = e - c2; nsrc = GUT_E; }
    else if (e < c4) { src = s_downt;   off = e - c3; nsrc = DOWNT_E; }
    else if (e < c5) { src = s_gum;     off = e - c4; nsrc = GUM_E; }
    else             { src = s_downm;   off = e - c5; nsrc = DOWNM_E; }
    ushort4 r;
    if (off < nsrc) {
        float4 v = *reinterpret_cast<const float4*>(src + off);
        r.x = f2bf(v.x); r.y = f2bf(v.y); r.z = f2bf(v.z); r.w = f2bf(v.w);
    } else {
        r.x = 0; r.y = 0; r.z = 0; r.w = 0;
    }
    *reinterpret_cast<ushort4*>(dst + e) = r;
}

// ----------------------------- bf16 MFMA GEMM ------------------------------
// C[M,N] = A[M,K] * W[N,K]^T. 128x128 tile, 4 waves of 64x64 (4x4 MFMAs).
// global_load_lds staging (no pad; XOR chunk swizzle vs bank conflicts).
// SK: write this slice's tile to C + slice*M*N (plain stores; summed later).
template<bool SK>
__device__ __forceinline__ void gemm_bt_body(
    const u16* __restrict__ A, const u16* __restrict__ W,
    float* __restrict__ C, int M, int N, int K, int kLen)
{
    __shared__ u16 As[128 * 32];
    __shared__ u16 Bs[128 * 32];
    int tid = threadIdx.x;
    int m0 = blockIdx.y * 128, n0 = blockIdx.x * 128;
    int kBase = SK ? blockIdx.z * kLen : 0;
    float* Cw = SK ? C + (size_t)blockIdx.z * M * N : C;
    int wave = tid >> 6, lane = tid & 63;
    int wm = (wave >> 1) * 64, wn = (wave & 1) * 64;
    int lrow = lane & 15;
    int kq = lane >> 4;
    int kx = (lrow & 3) ^ ((lrow >> 2) & 3);
    int ko = (kq ^ kx) * 8;           // swizzled LDS chunk offset for frags

    int rL = lane >> 2, cL = lane & 3;
    int cG = cL ^ ((rL & 3) ^ ((rL >> 2) & 3));
    int R0 = wave * 32 + rL;
    int R1 = R0 + 16;
    const u16* gA0 = A + (size_t)(m0 + R0) * K + kBase + cG * 8;
    const u16* gA1 = A + (size_t)(m0 + R1) * K + kBase + cG * 8;
    const u16* gB0 = W + (size_t)(n0 + R0) * K + kBase + cG * 8;
    const u16* gB1 = W + (size_t)(n0 + R1) * K + kBase + cG * 8;
    u16* lA0 = &As[(wave * 32) * 32];
    u16* lA1 = &As[(wave * 32 + 16) * 32];
    u16* lB0 = &Bs[(wave * 32) * 32];
    u16* lB1 = &Bs[(wave * 32 + 16) * 32];

    f32x4 acc[4][4];
    #pragma unroll
    for (int i = 0; i < 4; i++)
        #pragma unroll
        for (int j = 0; j < 4; j++) {
            acc[i][j][0] = 0.f; acc[i][j][1] = 0.f;
            acc[i][j][2] = 0.f; acc[i][j][3] = 0.f;
        }

    for (int kt = 0; kt < kLen; kt += 32) {
        __syncthreads();
        gld_lds16(gA0 + kt, lA0);
        gld_lds16(gA1 + kt, lA1);
        gld_lds16(gB0 + kt, lB0);
        gld_lds16(gB1 + kt, lB1);
        __syncthreads();
        bf16x8 af[4], bfr[4];
        #pragma unroll
        for (int i = 0; i < 4; i++) {
            af[i]  = *reinterpret_cast<const bf16x8*>(&As[(wm + i * 16 + lrow) * 32 + ko]);
            bfr[i] = *reinterpret_cast<const bf16x8*>(&Bs[(wn + i * 16 + lrow) * 32 + ko]);
        }
        #pragma unroll
        for (int i = 0; i < 4; i++)
            #pragma unroll
            for (int j = 0; j < 4; j++)
                acc[i][j] = __builtin_amdgcn_mfma_f32_16x16x32_bf16(af[i], bfr[j], acc[i][j], 0, 0, 0);
    }

    // C/D layout: col = lane&15, row = (lane>>4)*4 + reg
    int rbase = m0 + wm + kq * 4;
    int cbase = n0 + wn + lrow;
    #pragma unroll
    for (int i = 0; i < 4; i++)
        #pragma unroll
        for (int j = 0; j < 4; j++)
            #pragma unroll
            for (int r = 0; r < 4; r++)
                Cw[(size_t)(rbase + i * 16 + r) * N + cbase + j * 16] = acc[i][j][r];
}

__global__ __launch_bounds__(256) void gemm_bt(
    const u16* __restrict__ A, const u16* __restrict__ W,
    float* __restrict__ C, int M, int N, int K)
{
    gemm_bt_body<false>(A, W, C, M, N, K, K);
}

__global__ __launch_bounds__(256) void gemm_bt_sk(
    const u16* __restrict__ A, const u16* __restrict__ W,
    float* __restrict__ C, int M, int N, int K, int kLen)
{
    gemm_bt_body<true>(A, W, C, M, N, K, kLen);
}

// --------------------- fused gate/up GEMM + SwiGLU -------------------------
// act[M,inter] = silu(A·Wg^T) * (A·Wu^T), Wg = W rows [0,inter),
// Wu = W rows [inter,2*inter). Block = 128(M) x 64(N) act tile; wave w
// computes gate+up 64x32 sub-tiles (4x2 MFMAs each). A staged once, shared.
__global__ __launch_bounds__(256) void gemm_swiglu(
    const u16* __restrict__ A, const u16* __restrict__ W,
    u16* __restrict__ act, int M, int inter, int K)
{
    __shared__ u16 As[128 * 32];
    __shared__ u16 Bgs[64 * 32];
    __shared__ u16 Bus[64 * 32];
    int tid = threadIdx.x;
    int m0 = blockIdx.y * 128, n0 = blockIdx.x * 64;
    int wave = tid >> 6, lane = tid & 63;
    int wm = (wave >> 1) * 64, wn = (wave & 1) * 32;
    int lrow = lane & 15;
    int kq = lane >> 4;
    int kx = (lrow & 3) ^ ((lrow >> 2) & 3);
    int ko = (kq ^ kx) * 8;

    int rL = lane >> 2, cL = lane & 3;
    int cG = cL ^ ((rL & 3) ^ ((rL >> 2) & 3));
    // A staging: wave covers rows wave*32..+31 (2 insts)
    int R0 = wave * 32 + rL, R1 = R0 + 16;
    const u16* gA0 = A + (size_t)(m0 + R0) * K + cG * 8;
    const u16* gA1 = A + (size_t)(m0 + R1) * K + cG * 8;
    u16* lA0 = &As[(wave * 32) * 32];
    u16* lA1 = &As[(wave * 32 + 16) * 32];
    // B staging: waves 0,1 -> gate rows 0..63; waves 2,3 -> up rows 0..63
    int wB = (wave & 1) * 32;
    int upsel = wave >> 1;
    int RB0 = wB + rL, RB1 = RB0 + 16;
    const u16* gB0 = W + (size_t)(upsel * inter + n0 + RB0) * K + cG * 8;
    const u16* gB1 = W + (size_t)(upsel * inter + n0 + RB1) * K + cG * 8;
    u16* lBb = upsel ? Bus : Bgs;
    u16* lB0 = &lBb[wB * 32];
    u16* lB1 = &lBb[(wB + 16) * 32];

    f32x4 accg[4][2], accu[4][2];
    #pragma unroll
    for (int i = 0; i < 4; i++)
        #pragma unroll
        for (int j = 0; j < 2; j++) {
            accg[i][j][0]=0.f; accg[i][j][1]=0.f; accg[i][j][2]=0.f; accg[i][j][3]=0.f;
            accu[i][j][0]=0.f; accu[i][j][1]=0.f; accu[i][j][2]=0.f; accu[i][j][3]=0.f;
        }

    for (int kt = 0; kt < K; kt += 32) {
        __syncthreads();
        gld_lds16(gA0 + kt, lA0);
        gld_lds16(gA1 + kt, lA1);
        gld_lds16(gB0 + kt, lB0);
        gld_lds16(gB1 + kt, lB1);
        __syncthreads();
        bf16x8 af[4], bg[2], bu[2];
        #pragma unroll
        for (int i = 0; i < 4; i++)
            af[i] = *reinterpret_cast<const bf16x8*>(&As[(wm + i * 16 + lrow) * 32 + ko]);
        #pragma unroll
        for (int j = 0; j < 2; j++) {
            bg[j] = *reinterpret_cast<const bf16x8*>(&Bgs[(wn + j * 16 + lrow) * 32 + ko]);
            bu[j] = *reinterpret_cast<const bf16x8*>(&Bus[(wn + j * 16 + lrow) * 32 + ko]);
        }
        #pragma unroll
        for (int i = 0; i < 4; i++)
            #pragma unroll
            for (int j = 0; j < 2; j++) {
                accg[i][j] = __builtin_amdgcn_mfma_f32_16x16x32_bf16(af[i], bg[j], accg[i][j], 0, 0, 0);
                accu[i][j] = __builtin_amdgcn_mfma_f32_16x16x32_bf16(af[i], bu[j], accu[i][j], 0, 0, 0);
            }
    }

    // C/D layout: col = lane&15, row = (lane>>4)*4 + reg
    int rbase = m0 + wm + kq * 4;
    int cbase = n0 + wn + lrow;
    #pragma unroll
    for (int i = 0; i < 4; i++)
        #pragma unroll
        for (int j = 0; j < 2; j++)
            #pragma unroll
            for (int r = 0; r < 4; r++) {
                float g = accg[i][j][r], u = accu[i][j][r];
                act[(size_t)(rbase + i * 16 + r) * inter + cbase + j * 16] =
                    f2bf(silu_f(g) * u);
            }
}

// ----------------- conv (depthwise, causal, width 4) + dt ------------------
__global__ __launch_bounds__(256) void conv_dt_kernel(
    const float* __restrict__ zx, const float* __restrict__ conv_w,
    const float* __restrict__ conv_b, const float* __restrict__ dt_bias,
    float* __restrict__ convout, float* __restrict__ dtbuf)
{
    int idx = blockIdx.x * 256 + threadIdx.x;   // over 4096*1168
    int bl = idx / 1168;
    int c  = idx - bl * 1168;
    int l  = bl & (LL - 1);
    if (c < CONVDIM) {
        const float* col = zx + (size_t)bl * NPROJ_PAD + DINNER + c;
        float acc = conv_b[c];
        #pragma unroll
        for (int i = 0; i < 4; i++) {
            int lt = l - 3 + i;
            float v = (lt >= 0) ? col[(long long)(lt - l) * NPROJ_PAD] : 0.f;
            acc = fmaf(v, conv_w[c * 4 + i], acc);
        }
        convout[(size_t)bl * CONVDIM + c] = silu_f(acc);
    } else {
        int h = c - CONVDIM;
        float v = zx[(size_t)bl * NPROJ_PAD + 2176 + h] + dt_bias[h];
        float sp = (v > 20.f) ? v : log1pf(__expf(v));
        dtbuf[(size_t)bl * NHEADS + h] = sp;
    }
}

// ----------------------- chunked SSM scan: phase 1 -------------------------
__global__ __launch_bounds__(256) void scan_phase1(
    const float* __restrict__ convout, const float* __restrict__ dtbuf,
    const float* __restrict__ A_log, float* __restrict__ Sc,
    float* __restrict__ Ptot)
{
    __shared__ u16 Blds[CHUNK * 64];     // 4 KB, bf16
    __shared__ float dtl[CHUNK];
    int blk = blockIdx.x;
    int c   = blk & 31;
    int bh  = blk >> 5;
    int b = bh >> 4, h = bh & 15;
    int nq = threadIdx.x >> 6;
    int p  = threadIdx.x & 63;
    size_t base = ((size_t)b * LL + (size_t)c * CHUNK) * CONVDIM;

    const float* Bsrc = convout + base + DINNER;
    #pragma unroll
    for (int i = threadIdx.x; i < CHUNK * 16; i += 256) {   // 512 float4s
        int t = i >> 4, q = i & 15;
        float4 v = *reinterpret_cast<const float4*>(&Bsrc[(size_t)t * CONVDIM + q * 4]);
        ushort4 r; r.x = f2bf(v.x); r.y = f2bf(v.y); r.z = f2bf(v.z); r.w = f2bf(v.w);
        *reinterpret_cast<ushort4*>(&Blds[t * 64 + q * 4]) = r;
    }
    const float* db = dtbuf + ((size_t)b * LL + (size_t)c * CHUNK) * NHEADS + h;
    if (threadIdx.x < CHUNK) dtl[threadIdx.x] = db[(size_t)threadIdx.x * NHEADS];
    __syncthreads();

    float Ah = -__expf(A_log[h]);
    const float* xb = convout + base + h * HEADDIM + p;

    float s[16];
    #pragma unroll
    for (int j = 0; j < 16; j++) s[j] = 0.f;
    float dtsum = 0.f;

    float xvc = xb[0];
    for (int t = 0; t < CHUNK; ++t) {
        float dt = dtl[t];
        float xv = xvc;
        int tn = (t < CHUNK - 1) ? t + 1 : CHUNK - 1;
        xvc = xb[(size_t)tn * CONVDIM];
        const uint4* Bp = reinterpret_cast<const uint4*>(&Blds[t * 64 + nq * 16]);
        uint4 b0 = Bp[0], b1 = Bp[1];
        u32 Bw[8] = { b0.x, b0.y, b0.z, b0.w, b1.x, b1.y, b1.z, b1.w };
        float dA = __expf(dt * Ah);
        dtsum += dt;
        float coef = dt * xv;
        #pragma unroll
        for (int w = 0; w < 8; w++) {
            float lo, hi; bf2f2(Bw[w], lo, hi);
            s[2 * w]     = fmaf(s[2 * w],     dA, coef * lo);
            s[2 * w + 1] = fmaf(s[2 * w + 1], dA, coef * hi);
        }
    }
    float* So = Sc + ((size_t)(bh * 4 + nq) * NCHUNK + c) * 1024 + p * 16;
    #pragma unroll
    for (int q = 0; q < 4; q++) {
        float4 v; v.x = s[q*4]; v.y = s[q*4+1]; v.z = s[q*4+2]; v.w = s[q*4+3];
        *reinterpret_cast<float4*>(So + q * 4) = v;
    }
    if (nq == 0 && p == 0) Ptot[bh * NCHUNK + c] = __expf(Ah * dtsum);
}

// ----------------------- chunked SSM scan: phase 2 -------------------------
__global__ __launch_bounds__(64) void scan_combine(
    const float* __restrict__ Sc, const float* __restrict__ Ptot,
    float* __restrict__ Sinit)
{
    int blk = blockIdx.x;
    int bh = blk >> 2;
    int p = threadIdx.x;
    float carry[16];
    #pragma unroll
    for (int j = 0; j < 16; j++) carry[j] = 0.f;
    for (int c = 0; c < NCHUNK; ++c) {
        size_t row = ((size_t)blk * NCHUNK + c) * 1024 + p * 16;
        float* o = Sinit + row;
        #pragma unroll
        for (int j = 0; j < 16; j++) o[j] = carry[j];
        float P = Ptot[bh * NCHUNK + c];
        const float* si = Sc + row;
        #pragma unroll
        for (int j = 0; j < 16; j++) carry[j] = fmaf(carry[j], P, si[j]);
    }
}

// ----------------------- chunked SSM scan: phase 3 -------------------------
__global__ __launch_bounds__(128) void scan_phase2(
    const float* __restrict__ convout, const float* __restrict__ dtbuf,
    const float* __restrict__ A_log, const float* __restrict__ Sinit,
    float* __restrict__ yp0, float* __restrict__ yp1)
{
    __shared__ u16 BClds[CHUNK * 128];   // 8 KB, bf16 (B 64 | C 64 per step)
    __shared__ float dtl[CHUNK];
    int blk = blockIdx.x;
    int c   = blk & 31;
    int bh  = blk >> 5;
    int b = bh >> 4, h = bh & 15;
    int nh = threadIdx.x >> 6;
    int p  = threadIdx.x & 63;
    size_t base = ((size_t)b * LL + (size_t)c * CHUNK) * CONVDIM;

    const float* BCsrc = convout + base + DINNER;
    #pragma unroll
    for (int i = threadIdx.x; i < CHUNK * 32; i += 128) {   // 1024 float4s
        int t = i >> 5, q = i & 31;
        float4 v = *reinterpret_cast<const float4*>(&BCsrc[(size_t)t * CONVDIM + q * 4]);
        ushort4 r; r.x = f2bf(v.x); r.y = f2bf(v.y); r.z = f2bf(v.z); r.w = f2bf(v.w);
        *reinterpret_cast<ushort4*>(&BClds[t * 128 + q * 4]) = r;
    }
    const float* db = dtbuf + ((size_t)b * LL + (size_t)c * CHUNK) * NHEADS + h;
    if (threadIdx.x < CHUNK) dtl[threadIdx.x] = db[(size_t)threadIdx.x * NHEADS];
    __syncthreads();

    float Ah = -__expf(A_log[h]);
    const float* xb = convout + base + h * HEADDIM + p;
    float* yb = (nh ? yp1 : yp0)
              + ((size_t)b * LL + (size_t)c * CHUNK) * DINNER + h * HEADDIM + p;

    float s[32];
    {
        const float* si0 = Sinit + ((size_t)(bh * 4 + nh * 2)     * NCHUNK + c) * 1024 + p * 16;
        const float* si1 = Sinit + ((size_t)(bh * 4 + nh * 2 + 1) * NCHUNK + c) * 1024 + p * 16;
        #pragma unroll
        for (int j = 0; j < 16; j++) { s[j] = si0[j]; s[16 + j] = si1[j]; }
    }

    float xvc = xb[0];
    for (int t = 0; t < CHUNK; ++t) {
        float dt = dtl[t];
        float xv = xvc;
        int tn = (t < CHUNK - 1) ? t + 1 : CHUNK - 1;
        xvc = xb[(size_t)tn * CONVDIM];
        const uint4* Bp = reinterpret_cast<const uint4*>(&BClds[t * 128 + nh * 32]);
        const uint4* Cp = reinterpret_cast<const uint4*>(&BClds[t * 128 + 64 + nh * 32]);
        uint4 b0 = Bp[0], b1 = Bp[1], b2 = Bp[2], b3 = Bp[3];
        uint4 c0 = Cp[0], c1 = Cp[1], c2 = Cp[2], c3 = Cp[3];
        u32 Bw[16] = { b0.x,b0.y,b0.z,b0.w, b1.x,b1.y,b1.z,b1.w,
                       b2.x,b2.y,b2.z,b2.w, b3.x,b3.y,b3.z,b3.w };
        u32 Cw[16] = { c0.x,c0.y,c0.z,c0.w, c1.x,c1.y,c1.z,c1.w,
                       c2.x,c2.y,c2.z,c2.w, c3.x,c3.y,c3.z,c3.w };
        float dA = __expf(dt * Ah);
        float coef = dt * xv;
        #pragma unroll
        for (int w = 0; w < 16; w++) {
            float blo, bhi; bf2f2(Bw[w], blo, bhi);
            s[2 * w]     = fmaf(s[2 * w],     dA, coef * blo);
            s[2 * w + 1] = fmaf(s[2 * w + 1], dA, coef * bhi);
        }
        float y0 = 0.f, y1 = 0.f, y2 = 0.f, y3 = 0.f;
        #pragma unroll
        for (int w = 0; w < 16; w += 2) {
            float cl0, ch0, cl1, ch1;
            bf2f2(Cw[w],     cl0, ch0);
            bf2f2(Cw[w + 1], cl1, ch1);
            y0 = fmaf(s[2 * w],     cl0, y0);
            y1 = fmaf(s[2 * w + 1], ch0, y1);
            y2 = fmaf(s[2 * w + 2], cl1, y2);
            y3 = fmaf(s[2 * w + 3], ch1, y3);
        }
        yb[(size_t)t * DINNER] = (y0 + y1) + (y2 + y3);
    }
}

// ------------- gated RMSNorm (yp0+yp1+xD)*silu(z), bf16 out ----------------
__global__ __launch_bounds__(256) void gated_rms_kernel(
    const float* __restrict__ yp0, const float* __restrict__ yp1,
    const float* __restrict__ convout, const float* __restrict__ zx,
    const float* __restrict__ Dv, const float* __restrict__ norm_w,
    u16* __restrict__ gout)
{
    int bl = blockIdx.x;
    int c = threadIdx.x * 4;
    float4 y0 = *reinterpret_cast<const float4*>(yp0 + (size_t)bl * DINNER + c);
    float4 y1 = *reinterpret_cast<const float4*>(yp1 + (size_t)bl * DINNER + c);
    float4 xv = *reinterpret_cast<const float4*>(convout + (size_t)bl * CONVDIM + c);
    float4 zv = *reinterpret_cast<const float4*>(zx + (size_t)bl * NPROJ_PAD + c);
    float Dh = Dv[c >> 6];
    float g0 = (y0.x + y1.x + xv.x * Dh) * silu_f(zv.x);
    float g1 = (y0.y + y1.y + xv.y * Dh) * silu_f(zv.y);
    float g2 = (y0.z + y1.z + xv.z * Dh) * silu_f(zv.z);
    float g3 = (y0.w + y1.w + xv.w * Dh) * silu_f(zv.w);
    float tot = block_sum(g0 * g0 + g1 * g1 + g2 * g2 + g3 * g3);
    float sc = rsqrtf(tot * (1.f / DINNER) + 1e-5f);
    float4 nw = *reinterpret_cast<const float4*>(norm_w + c);
    ushort4 o;
    o.x = f2bf(g0 * sc * nw.x); o.y = f2bf(g1 * sc * nw.y);
    o.z = f2bf(g2 * sc * nw.z); o.w = f2bf(g3 * sc * nw.w);
    *reinterpret_cast<ushort4*>(gout + (size_t)bl * DINNER + c) = o;
}

// ---- residual + 4 split-K partials + RMSNorm (no weight), f32 out ---------
__global__ void residual_rms_sk_kernel(
    const float* __restrict__ a, const float* __restrict__ pbuf,
    float* __restrict__ outf, int ncols, int rows)
{
    int row = blockIdx.x;
    int c = threadIdx.x * 4;
    size_t slice = (size_t)rows * ncols;
    size_t off = (size_t)row * ncols + c;
    float4 va = *reinterpret_cast<const float4*>(a + off);
    float4 p0 = *reinterpret_cast<const float4*>(pbuf + off);
    float4 p1 = *reinterpret_cast<const float4*>(pbuf + slice + off);
    float4 p2 = *reinterpret_cast<const float4*>(pbuf + 2 * slice + off);
    float4 p3 = *reinterpret_cast<const float4*>(pbuf + 3 * slice + off);
    float v0 = va.x + ((p0.x + p1.x) + (p2.x + p3.x));
    float v1 = va.y + ((p0.y + p1.y) + (p2.y + p3.y));
    float v2 = va.z + ((p0.z + p1.z) + (p2.z + p3.z));
    float v3 = va.w + ((p0.w + p1.w) + (p2.w + p3.w));
    float tot = block_sum(v0 * v0 + v1 * v1 + v2 * v2 + v3 * v3);
    float sc = rsqrtf(tot / (float)ncols + 1e-5f);
    float4 o; o.x = v0 * sc; o.y = v1 * sc; o.z = v2 * sc; o.w = v3 * sc;
    *reinterpret_cast<float4*>(outf + off) = o;
}

// ------------- transpose per batch: in (R,C) -> out (C,R), dual write ------
__global__ __launch_bounds__(256) void transpose_dual_kernel(
    const float* __restrict__ in, u16* __restrict__ outb,
    float* __restrict__ outf, int R, int C)
{
    __shared__ float tile[32][33];
    int b = blockIdx.z;
    int c0 = blockIdx.x * 32, r0 = blockIdx.y * 32;
    const float* ip = in + (size_t)b * R * C;
    for (int i = threadIdx.y; i < 32; i += 8)
        tile[i][threadIdx.x] = ip[(size_t)(r0 + i) * C + c0 + threadIdx.x];
    __syncthreads();
    size_t ob = (size_t)b * R * C;
    for (int i = threadIdx.y; i < 32; i += 8) {
        float v = tile[threadIdx.x][i];
        size_t oi = ob + (size_t)(c0 + i) * R + r0 + threadIdx.x;
        outf[oi] = v;
        outb[oi] = f2bf(v);
    }
}

// ---------------------------------------------------------------------------
extern "C" void kernel_launch(void* const* d_in, const int* in_sizes, int n_in,
                              void* d_out, int out_size, void* d_ws, size_t ws_size,
                              hipStream_t stream)
{
    const float* hid      = (const float*)d_in[0];
    const float* in_proj  = (const float*)d_in[1];
    const float* conv_w   = (const float*)d_in[2];
    const float* conv_b   = (const float*)d_in[3];
    const float* dt_bias  = (const float*)d_in[4];
    const float* A_log    = (const float*)d_in[5];
    const float* Dv       = (const float*)d_in[6];
    const float* norm_w   = (const float*)d_in[7];
    const float* out_proj = (const float*)d_in[8];
    const float* gu_t     = (const float*)d_in[9];
    const float* down_t   = (const float*)d_in[10];
    const float* gu_m     = (const float*)d_in[11];
    const float* down_m   = (const float*)d_in[12];
    float* outp = (float*)d_out;

    char* ws = (char*)d_ws;
    u16* bf        = (u16*)ws;
    u16* hid_bf    = bf;
    u16* w_inproj  = bf + HID_E;
    u16* w_outproj = w_inproj + INPROJ_P_E;
    u16* w_gut     = w_outproj + OUTPROJ_E;
    u16* w_downt   = w_gut + GUT_E;
    u16* w_gum     = w_downt + DOWNT_E;
    u16* w_downm   = w_gum + GUM_E;
    size_t o = (size_t)(CONV_TOT_E * 2);
    auto alloc = [&](size_t bytes) { size_t r = o; o = (o + bytes + 255) & ~(size_t)255; return r; };
    size_t dt_off  = alloc(4096 * 16 * 4);
    size_t g_off   = alloc((size_t)4096 * 1024 * 2);
    size_t h1_off  = alloc((size_t)4096 * 512 * 4);
    size_t Pt_off  = alloc(2048 * 4);
    // ---- MLP region (live step 8+); Sc/Sinit OVERLAY it (live steps 4-5).
    // Region must hold Sc+Sinit = 2 x 8192*1024*4 = 67,108,864 B.
    // Sum below (xtb..act2) = 57,671,680 B -> pad 10 MB => 68,157,440 B. OK.
    size_t xtb_off = alloc((size_t)2048 * 1024 * 2);
    size_t xtf_off = alloc((size_t)2048 * 1024 * 4);
    size_t act1_off= alloc((size_t)2048 * 2816 * 2);
    size_t x2_off  = alloc((size_t)2048 * 1024 * 4);
    size_t h2b_off = alloc((size_t)4096 * 512 * 2);
    size_t h2f_off = alloc((size_t)4096 * 512 * 4);
    size_t act2_off= alloc((size_t)4096 * 1536 * 2);
    size_t pad_off = alloc((size_t)10 * 1024 * 1024);
    size_t Sc_off  = xtb_off;                          // 33.55 MB
    size_t Si_off  = xtb_off + (size_t)8192 * 1024 * 4;// 33.55 MB
    (void)pad_off;
    // overlay region R_off: {zxbcdt, convout, yp0} live until gated_rms;
    // then split-K partials (33.5 MB) time-share it.
    size_t R_off   = o;
    size_t zx_off  = R_off;
    size_t cv_off  = zx_off + (size_t)4096 * NPROJ_PAD * 4;
    size_t y_off   = cv_off + (size_t)4096 * CONVDIM * 4;
    size_t sk_off  = R_off;

    float* zx      = (float*)(ws + zx_off);
    float* convout = (float*)(ws + cv_off);
    float* ybuf    = (float*)(ws + y_off);           // yp0
    float* dtbuf   = (float*)(ws + dt_off);
    u16*   g_bf    = (u16*)(ws + g_off);
    float* h1      = (float*)(ws + h1_off);
    u16*   xt_bf   = (u16*)(ws + xtb_off);
    float* xt_f    = (float*)(ws + xtf_off);
    u16*   act1    = (u16*)(ws + act1_off);
    float* x2      = (float*)(ws + x2_off);
    u16*   h2_bf   = (u16*)(ws + h2b_off);
    float* h2_f    = (float*)(ws + h2f_off);
    u16*   act2    = (u16*)(ws + act2_off);
    float* skbuf   = (float*)(ws + sk_off);          // split-K partials x4
    float* Sc      = (float*)(ws + Sc_off);          // yp1 after scan_combine
    float* Sinit   = (float*)(ws + Si_off);
    float* Ptot    = (float*)(ws + Pt_off);

    // 1) convert weights + hidden to bf16
    convert_all_kernel<<<14464, 256, 0, stream>>>(
        hid, in_proj, out_proj, gu_t, down_t, gu_m, down_m, bf);

    // 2) zxbcdt = hidden @ in_proj^T  (576 blocks)
    gemm_bt<<<dim3(NPROJ_PAD / 128, 4096 / 128), 256, 0, stream>>>(
        hid_bf, w_inproj, zx, 4096, NPROJ_PAD, 512);

    // 3) conv + dt
    conv_dt_kernel<<<18688, 256, 0, stream>>>(zx, conv_w, conv_b, dt_bias, convout, dtbuf);

    // 4) chunked SSM scan (CHUNK=32; phase2 halves; yp0=ybuf, yp1=Sc reuse)
    scan_phase1<<<2048, 256, 0, stream>>>(convout, dtbuf, A_log, Sc, Ptot);
    scan_combine<<<256, 64, 0, stream>>>(Sc, Ptot, Sinit);
    scan_phase2<<<2048, 128, 0, stream>>>(convout, dtbuf, A_log, Sinit, ybuf, Sc);

    // 5) gated RMSNorm -> bf16  (zx/convout/ybuf dead after this)
    gated_rms_kernel<<<4096, 256, 0, stream>>>(ybuf, Sc, convout, zx, Dv, norm_w, g_bf);

    // 6) out_proj GEMM, split-K x4 -> partials in skbuf (512 blocks)
    gemm_bt_sk<<<dim3(512 / 128, 4096 / 128, 4), 256, 0, stream>>>(
        g_bf, w_outproj, skbuf, 4096, 512, 1024, 256);

    // 7) h1 = rms(hidden + sum partials)
    residual_rms_sk_kernel<<<4096, 128, 0, stream>>>(hid, skbuf, h1, 512, 4096);

    // 8) transpose (B,1024,512) -> (B,512,1024)  [overwrites Sc region - dead]
    transpose_dual_kernel<<<dim3(16, 32, 4), dim3(32, 8), 0, stream>>>(h1, xt_bf, xt_f, 1024, 512);

    // 9) token MLP fused: act1 = swiglu(xt @ gu_t^T)  (704 blocks, no t1)
    gemm_swiglu<<<dim3(INTER_T / 64, 2048 / 128), 256, 0, stream>>>(
        xt_bf, w_gut, act1, 2048, INTER_T, 1024);

    // 10) down_t GEMM, split-K x4 -> partials in skbuf (512 blocks)
    gemm_bt_sk<<<dim3(1024 / 128, 2048 / 128, 4), 256, 0, stream>>>(
        act1, w_downt, skbuf, 2048, 1024, 2816, 704);

    // 11) x2 = rms(xt_f + sum partials)
    residual_rms_sk_kernel<<<2048, 256, 0, stream>>>(xt_f, skbuf, x2, 1024, 2048);

    // 12) transpose back (B,512,1024) -> (B,1024,512)
    transpose_dual_kernel<<<dim3(32, 16, 4), dim3(32, 8), 0, stream>>>(x2, h2_bf, h2_f, 512, 1024);

    // 13) channel MLP fused: act2 = swiglu(h2 @ gu_m^T)  (768 blocks, no t3)
    gemm_swiglu<<<dim3(INTER_M / 64, 4096 / 128), 256, 0, stream>>>(
        h2_bf, w_gum, act2, 4096, INTER_M, 512);

    // 14) down_m GEMM, split-K x4 -> partials in skbuf (512 blocks)
    gemm_bt_sk<<<dim3(512 / 128, 4096 / 128, 4), 256, 0, stream>>>(
        act2, w_downm, skbuf, 4096, 512, 1536, 384);

    // 15) out = rms(h2_f + sum partials)
    residual_rms_sk_kernel<<<4096, 128, 0, stream>>>(h2_f, skbuf, outp, 512, 4096);
}

// Round 13
// 369.754 us; speedup vs baseline: 1.1902x; 1.1113x over previous
//
#include <hip/hip_runtime.h>

// ---------------------------------------------------------------------------
// Mamba2 hybrid block. GEMMs: bf16 MFMA 16x16x32, f32 accumulate, m97-style
// global_load_lds(16B) staging with XOR bank swizzle. Small-N GEMMs use
// split-K x4 into SEPARATE partial buffers; partials summed in the
// downstream residual_rms kernel. MLP gu-GEMMs fuse SwiGLU in the epilogue.
// Scan: MFMA chunked (Mamba2 quadratic form) — R10-R12 showed the VALU scan
// plateaus at ~50 us; per chunk: G=C·B^T, Yintra=(mask*decay*dt*G)·X,
// Sc=X^T·B_hat, and post-combine Yinter=(dAcum*C)·Sinit^T. All use the
// verified gemm_bt fragment conventions.
// ---------------------------------------------------------------------------

#define BB 4
#define LL 1024
#define DMODEL 512
#define DINNER 1024
#define NHEADS 16
#define HEADDIM 64
#define DSTATE 64
#define CONVDIM 1152        // DINNER + 2*DSTATE
#define NPROJ 2192          // D_IN_PROJ
#define NPROJ_PAD 2304      // padded to multiple of 128
#define INTER_T 2816
#define INTER_M 1536
#define NCHUNK 32
#define CHUNK 32

typedef __bf16 bf16x8 __attribute__((ext_vector_type(8)));
typedef float  f32x4  __attribute__((ext_vector_type(4)));
typedef unsigned short u16;
typedef unsigned int   u32;

__device__ __forceinline__ u16 f2bf(float x) {
    union { float f; u32 u; } v; v.f = x;
    u32 u = v.u;
    return (u16)((u + 0x7fffu + ((u >> 16) & 1u)) >> 16);
}
__device__ __forceinline__ float silu_f(float x) {
    return x / (1.f + __expf(-x));
}
__device__ __forceinline__ float bf2f(u16 w) {
    union { u32 u; float f; } a; a.u = ((u32)w) << 16; return a.f;
}

// async global->LDS, 16B per lane; LDS dest is wave-uniform base + lane*16
__device__ __forceinline__ void gld_lds16(const u16* g, u16* l) {
    __builtin_amdgcn_global_load_lds(
        (const __attribute__((address_space(1))) unsigned int*)g,
        (__attribute__((address_space(3))) unsigned int*)l, 16, 0, 0);
}

// --------------------------- block-wide sum --------------------------------
__device__ __forceinline__ float block_sum(float v) {
    #pragma unroll
    for (int off = 32; off > 0; off >>= 1) v += __shfl_xor(v, off, 64);
    __shared__ float red[4];
    int w = threadIdx.x >> 6;
    int nwv = blockDim.x >> 6;
    if ((threadIdx.x & 63) == 0) red[w] = v;
    __syncthreads();
    float tot = red[0];
    for (int i = 1; i < nwv; i++) tot += red[i];
    return tot;
}

// --------------------- f32 -> bf16 convert (all weights + hidden) ----------
#define HID_E      2097152LL   // 4096*512
#define INPROJ_P_E 1179648LL   // 2304*512
#define INPROJ_S_E 1122304LL   // 2192*512
#define OUTPROJ_E   524288LL   // 512*1024
#define GUT_E      5767168LL   // 5632*1024
#define DOWNT_E    2883584LL   // 1024*2816
#define GUM_E      1572864LL   // 3072*512
#define DOWNM_E     786432LL   // 512*1536
#define CONV_TOT_E 14811136LL

__global__ __launch_bounds__(256) void convert_all_kernel(
    const float* __restrict__ s_hid, const float* __restrict__ s_inproj,
    const float* __restrict__ s_outproj, const float* __restrict__ s_gut,
    const float* __restrict__ s_downt, const float* __restrict__ s_gum,
    const float* __restrict__ s_downm, u16* __restrict__ dst)
{
    long long idx = (long long)blockIdx.x * 256 + threadIdx.x;
    long long e = idx * 4;
    if (e >= CONV_TOT_E) return;
    const float* src; long long off, nsrc;
    long long c0 = HID_E;
    long long c1 = c0 + INPROJ_P_E;
    long long c2 = c1 + OUTPROJ_E;
    long long c3 = c2 + GUT_E;
    long long c4 = c3 + DOWNT_E;
    long long c5 = c4 + GUM_E;
    if      (e < c0) { src = s_hid;     off = e;      nsrc = HID_E; }
    else if (e < c1) { src = s_inproj;  off = e - c0; nsrc = INPROJ_S_E; }
    else if (e < c2) { src = s_outproj; off = e - c1; nsrc = OUTPROJ_E; }
    else if (e < c3) { src = s_gut;     off = e - c2; nsrc = GUT_E; }
    else if (e < c4) { src = s_downt;   off = e - c3; nsrc = DOWNT_E; }
    else if (e < c5) { src = s_gum;     off = e - c4; nsrc = GUM_E; }
    else             { src = s_downm;   off = e - c5; nsrc = DOWNM_E; }
    ushort4 r;
    if (off < nsrc) {
        float4 v = *reinterpret_cast<const float4*>(src + off);
        r.x = f2bf(v.x); r.y = f2bf(v.y); r.z = f2bf(v.z); r.w = f2bf(v.w);
    } else {
        r.x = 0; r.y = 0; r.z = 0; r.w = 0;
    }
    *reinterpret_cast<ushort4*>(dst + e) = r;
}

// ----------------------------- bf16 MFMA GEMM ------------------------------
template<bool SK>
__device__ __forceinline__ void gemm_bt_body(
    const u16* __restrict__ A, const u16* __restrict__ W,
    float* __restrict__ C, int M, int N, int K, int kLen)
{
    __shared__ u16 As[128 * 32];
    __shared__ u16 Bs[128 * 32];
    int tid = threadIdx.x;
    int m0 = blockIdx.y * 128, n0 = blockIdx.x * 128;
    int kBase = SK ? blockIdx.z * kLen : 0;
    float* Cw = SK ? C + (size_t)blockIdx.z * M * N : C;
    int wave = tid >> 6, lane = tid & 63;
    int wm = (wave >> 1) * 64, wn = (wave & 1) * 64;
    int lrow = lane & 15;
    int kq = lane >> 4;
    int kx = (lrow & 3) ^ ((lrow >> 2) & 3);
    int ko = (kq ^ kx) * 8;

    int rL = lane >> 2, cL = lane & 3;
    int cG = cL ^ ((rL & 3) ^ ((rL >> 2) & 3));
    int R0 = wave * 32 + rL;
    int R1 = R0 + 16;
    const u16* gA0 = A + (size_t)(m0 + R0) * K + kBase + cG * 8;
    const u16* gA1 = A + (size_t)(m0 + R1) * K + kBase + cG * 8;
    const u16* gB0 = W + (size_t)(n0 + R0) * K + kBase + cG * 8;
    const u16* gB1 = W + (size_t)(n0 + R1) * K + kBase + cG * 8;
    u16* lA0 = &As[(wave * 32) * 32];
    u16* lA1 = &As[(wave * 32 + 16) * 32];
    u16* lB0 = &Bs[(wave * 32) * 32];
    u16* lB1 = &Bs[(wave * 32 + 16) * 32];

    f32x4 acc[4][4];
    #pragma unroll
    for (int i = 0; i < 4; i++)
        #pragma unroll
        for (int j = 0; j < 4; j++) {
            acc[i][j][0] = 0.f; acc[i][j][1] = 0.f;
            acc[i][j][2] = 0.f; acc[i][j][3] = 0.f;
        }

    for (int kt = 0; kt < kLen; kt += 32) {
        __syncthreads();
        gld_lds16(gA0 + kt, lA0);
        gld_lds16(gA1 + kt, lA1);
        gld_lds16(gB0 + kt, lB0);
        gld_lds16(gB1 + kt, lB1);
        __syncthreads();
        bf16x8 af[4], bfr[4];
        #pragma unroll
        for (int i = 0; i < 4; i++) {
            af[i]  = *reinterpret_cast<const bf16x8*>(&As[(wm + i * 16 + lrow) * 32 + ko]);
            bfr[i] = *reinterpret_cast<const bf16x8*>(&Bs[(wn + i * 16 + lrow) * 32 + ko]);
        }
        #pragma unroll
        for (int i = 0; i < 4; i++)
            #pragma unroll
            for (int j = 0; j < 4; j++)
                acc[i][j] = __builtin_amdgcn_mfma_f32_16x16x32_bf16(af[i], bfr[j], acc[i][j], 0, 0, 0);
    }

    int rbase = m0 + wm + kq * 4;
    int cbase = n0 + wn + lrow;
    #pragma unroll
    for (int i = 0; i < 4; i++)
        #pragma unroll
        for (int j = 0; j < 4; j++)
            #pragma unroll
            for (int r = 0; r < 4; r++)
                Cw[(size_t)(rbase + i * 16 + r) * N + cbase + j * 16] = acc[i][j][r];
}

__global__ __launch_bounds__(256) void gemm_bt(
    const u16* __restrict__ A, const u16* __restrict__ W,
    float* __restrict__ C, int M, int N, int K)
{
    gemm_bt_body<false>(A, W, C, M, N, K, K);
}

__global__ __launch_bounds__(256) void gemm_bt_sk(
    const u16* __restrict__ A, const u16* __restrict__ W,
    float* __restrict__ C, int M, int N, int K, int kLen)
{
    gemm_bt_body<true>(A, W, C, M, N, K, kLen);
}

// --------------------- fused gate/up GEMM + SwiGLU -------------------------
__global__ __launch_bounds__(256) void gemm_swiglu(
    const u16* __restrict__ A, const u16* __restrict__ W,
    u16* __restrict__ act, int M, int inter, int K)
{
    __shared__ u16 As[128 * 32];
    __shared__ u16 Bgs[64 * 32];
    __shared__ u16 Bus[64 * 32];
    int tid = threadIdx.x;
    int m0 = blockIdx.y * 128, n0 = blockIdx.x * 64;
    int wave = tid >> 6, lane = tid & 63;
    int wm = (wave >> 1) * 64, wn = (wave & 1) * 32;
    int lrow = lane & 15;
    int kq = lane >> 4;
    int kx = (lrow & 3) ^ ((lrow >> 2) & 3);
    int ko = (kq ^ kx) * 8;

    int rL = lane >> 2, cL = lane & 3;
    int cG = cL ^ ((rL & 3) ^ ((rL >> 2) & 3));
    int R0 = wave * 32 + rL, R1 = R0 + 16;
    const u16* gA0 = A + (size_t)(m0 + R0) * K + cG * 8;
    const u16* gA1 = A + (size_t)(m0 + R1) * K + cG * 8;
    u16* lA0 = &As[(wave * 32) * 32];
    u16* lA1 = &As[(wave * 32 + 16) * 32];
    int wB = (wave & 1) * 32;
    int upsel = wave >> 1;
    int RB0 = wB + rL, RB1 = RB0 + 16;
    const u16* gB0 = W + (size_t)(upsel * inter + n0 + RB0) * K + cG * 8;
    const u16* gB1 = W + (size_t)(upsel * inter + n0 + RB1) * K + cG * 8;
    u16* lBb = upsel ? Bus : Bgs;
    u16* lB0 = &lBb[wB * 32];
    u16* lB1 = &lBb[(wB + 16) * 32];

    f32x4 accg[4][2], accu[4][2];
    #pragma unroll
    for (int i = 0; i < 4; i++)
        #pragma unroll
        for (int j = 0; j < 2; j++) {
            accg[i][j][0]=0.f; accg[i][j][1]=0.f; accg[i][j][2]=0.f; accg[i][j][3]=0.f;
            accu[i][j][0]=0.f; accu[i][j][1]=0.f; accu[i][j][2]=0.f; accu[i][j][3]=0.f;
        }

    for (int kt = 0; kt < K; kt += 32) {
        __syncthreads();
        gld_lds16(gA0 + kt, lA0);
        gld_lds16(gA1 + kt, lA1);
        gld_lds16(gB0 + kt, lB0);
        gld_lds16(gB1 + kt, lB1);
        __syncthreads();
        bf16x8 af[4], bg[2], bu[2];
        #pragma unroll
        for (int i = 0; i < 4; i++)
            af[i] = *reinterpret_cast<const bf16x8*>(&As[(wm + i * 16 + lrow) * 32 + ko]);
        #pragma unroll
        for (int j = 0; j < 2; j++) {
            bg[j] = *reinterpret_cast<const bf16x8*>(&Bgs[(wn + j * 16 + lrow) * 32 + ko]);
            bu[j] = *reinterpret_cast<const bf16x8*>(&Bus[(wn + j * 16 + lrow) * 32 + ko]);
        }
        #pragma unroll
        for (int i = 0; i < 4; i++)
            #pragma unroll
            for (int j = 0; j < 2; j++) {
                accg[i][j] = __builtin_amdgcn_mfma_f32_16x16x32_bf16(af[i], bg[j], accg[i][j], 0, 0, 0);
                accu[i][j] = __builtin_amdgcn_mfma_f32_16x16x32_bf16(af[i], bu[j], accu[i][j], 0, 0, 0);
            }
    }

    int rbase = m0 + wm + kq * 4;
    int cbase = n0 + wn + lrow;
    #pragma unroll
    for (int i = 0; i < 4; i++)
        #pragma unroll
        for (int j = 0; j < 2; j++)
            #pragma unroll
            for (int r = 0; r < 4; r++) {
                float g = accg[i][j][r], u = accu[i][j][r];
                act[(size_t)(rbase + i * 16 + r) * inter + cbase + j * 16] =
                    f2bf(silu_f(g) * u);
            }
}

// ----------------- conv (depthwise, causal, width 4) + dt ------------------
__global__ __launch_bounds__(256) void conv_dt_kernel(
    const float* __restrict__ zx, const float* __restrict__ conv_w,
    const float* __restrict__ conv_b, const float* __restrict__ dt_bias,
    float* __restrict__ convout, float* __restrict__ dtbuf)
{
    int idx = blockIdx.x * 256 + threadIdx.x;   // over 4096*1168
    int bl = idx / 1168;
    int c  = idx - bl * 1168;
    int l  = bl & (LL - 1);
    if (c < CONVDIM) {
        const float* col = zx + (size_t)bl * NPROJ_PAD + DINNER + c;
        float acc = conv_b[c];
        #pragma unroll
        for (int i = 0; i < 4; i++) {
            int lt = l - 3 + i;
            float v = (lt >= 0) ? col[(long long)(lt - l) * NPROJ_PAD] : 0.f;
            acc = fmaf(v, conv_w[c * 4 + i], acc);
        }
        convout[(size_t)bl * CONVDIM + c] = silu_f(acc);
    } else {
        int h = c - CONVDIM;
        float v = zx[(size_t)bl * NPROJ_PAD + 2176 + h] + dt_bias[h];
        float sp = (v > 20.f) ? v : log1pf(__expf(v));
        dtbuf[(size_t)bl * NHEADS + h] = sp;
    }
}

// -------------------- MFMA chunk scan: pass 1 ------------------------------
// block = (b*16+h)*32 + c, 64 thr (1 wave). Computes per chunk:
//   G = C·B^T (32x32, K=64); W = mask*decay*dt ⊙ G (bf16, LDS);
//   Yintra = W·X (32t x 64p, K=32)        -> yp0
//   Sc     = X^T·B_hat (64p x 64n, K=32)  -> Sc   (B_hat = w_t*dt_t*B)
//   Ptot   = exp(Ah*cumTot)
// Layouts: A/W-operands row-major K-contig bf16x8 (gemm_bt convention);
// D: col=lane&15(+16j), row=kq*4+r(+16i). LDS strides 72/40 kill conflicts.
__global__ __launch_bounds__(64) void scan_mfma1(
    const float* __restrict__ convout, const float* __restrict__ dtbuf,
    const float* __restrict__ A_log, float* __restrict__ Sc,
    float* __restrict__ Ptot, float* __restrict__ yp0)
{
    __shared__ u16 Blds[32 * 72];    // raw B bf16 [t][n]
    __shared__ u16 Clds[32 * 72];    // raw C bf16 [t][n]
    __shared__ u16 Xt[64 * 40];      // x^T bf16 [p][t]
    __shared__ u16 Bht[64 * 40];     // (w_t*dt_t*B)^T bf16 [n][t]
    __shared__ u16 Wlds[32 * 40];    // W bf16 [t][t']
    __shared__ float dtl[32], cuml[32], warr[32];

    int blk = blockIdx.x;
    int c   = blk & 31;
    int bh  = blk >> 5;
    int b = bh >> 4, h = bh & 15;
    int lane = threadIdx.x;
    int lrow = lane & 15, kq = lane >> 4;
    size_t base = ((size_t)b * LL + (size_t)c * CHUNK) * CONVDIM;
    float Ah = -__expf(A_log[h]);

    // ---- stage dt, B, C, Xt ----
    if (lane < 32)
        dtl[lane] = dtbuf[((size_t)b * LL + (size_t)c * CHUNK + lane) * NHEADS + h];
    #pragma unroll
    for (int it = 0; it < 16; ++it) {           // 1024 float4s of B|C
        int idx = it * 64 + lane;
        int t = idx >> 5, q = idx & 31;
        float4 v = *reinterpret_cast<const float4*>(
            &convout[base + (size_t)t * CONVDIM + DINNER + q * 4]);
        ushort4 r4; r4.x = f2bf(v.x); r4.y = f2bf(v.y); r4.z = f2bf(v.z); r4.w = f2bf(v.w);
        if (q < 16) *reinterpret_cast<ushort4*>(&Blds[t * 72 + q * 4]) = r4;
        else        *reinterpret_cast<ushort4*>(&Clds[t * 72 + (q - 16) * 4]) = r4;
    }
    #pragma unroll
    for (int t = 0; t < 32; ++t) {
        float v = convout[base + (size_t)t * CONVDIM + h * HEADDIM + lane];
        Xt[lane * 40 + t] = f2bf(v);
    }
    __syncthreads();

    // ---- cumulative dt (broadcast reads, no serial LDS chain) ----
    float s_inc = 0.f, s_all = 0.f;
    #pragma unroll
    for (int j = 0; j < 32; ++j) {
        float v = dtl[j];
        s_all += v;
        if (j <= lane) s_inc += v;
    }
    if (lane < 32) {
        cuml[lane] = s_inc;
        warr[lane] = __expf(Ah * (s_all - s_inc)) * dtl[lane];
    }
    float cumTot = s_all;
    __syncthreads();

    // ---- build B_hat^T [n][t] ----
    #pragma unroll
    for (int t = 0; t < 32; ++t)
        Bht[lane * 40 + t] = f2bf(warr[t] * bf2f(Blds[t * 72 + lane]));

    // ---- G = C·B^T ----
    f32x4 accG[2][2];
    #pragma unroll
    for (int i = 0; i < 2; i++)
        #pragma unroll
        for (int j = 0; j < 2; j++) {
            accG[i][j][0]=0.f; accG[i][j][1]=0.f; accG[i][j][2]=0.f; accG[i][j][3]=0.f;
        }
    #pragma unroll
    for (int ks = 0; ks < 2; ++ks) {
        bf16x8 af[2], bfr[2];
        #pragma unroll
        for (int i = 0; i < 2; i++) {
            af[i]  = *reinterpret_cast<const bf16x8*>(&Clds[(16*i + lrow) * 72 + ks*32 + kq*8]);
            bfr[i] = *reinterpret_cast<const bf16x8*>(&Blds[(16*i + lrow) * 72 + ks*32 + kq*8]);
        }
        #pragma unroll
        for (int i = 0; i < 2; i++)
            #pragma unroll
            for (int j = 0; j < 2; j++)
                accG[i][j] = __builtin_amdgcn_mfma_f32_16x16x32_bf16(af[i], bfr[j], accG[i][j], 0, 0, 0);
    }

    // ---- W = mask * exp(Ah*(cum_t - cum_t')) * dt_t' * G -> Wlds[t][t'] ----
    float ctp0 = cuml[lrow],      dtp0 = dtl[lrow];
    float ctp1 = cuml[16 + lrow], dtp1 = dtl[16 + lrow];
    #pragma unroll
    for (int i = 0; i < 2; i++)
        #pragma unroll
        for (int r = 0; r < 4; r++) {
            int t = 16*i + kq*4 + r;
            float ct = cuml[t];
            #pragma unroll
            for (int j = 0; j < 2; j++) {
                int tp = 16*j + lrow;
                float ctp = j ? ctp1 : ctp0;
                float dtp = j ? dtp1 : dtp0;
                float g = accG[i][j][r];
                float wv = (tp <= t) ? __expf(Ah * (ct - ctp)) * dtp * g : 0.f;
                Wlds[t * 40 + tp] = f2bf(wv);
            }
        }
    __syncthreads();   // Wlds + Bht visible

    // ---- Yintra = W·X  (M=32 t, N=64 p, K=32 t') ----
    bf16x8 xf[4];
    #pragma unroll
    for (int j = 0; j < 4; j++)
        xf[j] = *reinterpret_cast<const bf16x8*>(&Xt[(16*j + lrow) * 40 + kq*8]);
    f32x4 accY[2][4];
    #pragma unroll
    for (int i = 0; i < 2; i++) {
        bf16x8 wf = *reinterpret_cast<const bf16x8*>(&Wlds[(16*i + lrow) * 40 + kq*8]);
        #pragma unroll
        for (int j = 0; j < 4; j++) {
            accY[i][j][0]=0.f; accY[i][j][1]=0.f; accY[i][j][2]=0.f; accY[i][j][3]=0.f;
            accY[i][j] = __builtin_amdgcn_mfma_f32_16x16x32_bf16(wf, xf[j], accY[i][j], 0, 0, 0);
        }
    }

    // ---- Sc = X^T·B_hat  (M=64 p, N=64 n, K=32 t) ----
    f32x4 accS[4][4];
    #pragma unroll
    for (int j = 0; j < 4; j++) {
        bf16x8 bb = *reinterpret_cast<const bf16x8*>(&Bht[(16*j + lrow) * 40 + kq*8]);
        #pragma unroll
        for (int i = 0; i < 4; i++) {
            accS[i][j][0]=0.f; accS[i][j][1]=0.f; accS[i][j][2]=0.f; accS[i][j][3]=0.f;
            accS[i][j] = __builtin_amdgcn_mfma_f32_16x16x32_bf16(xf[i], bb, accS[i][j], 0, 0, 0);
        }
    }

    // ---- writes ----
    float* yb = yp0 + ((size_t)b * LL + (size_t)c * CHUNK) * DINNER + h * HEADDIM;
    #pragma unroll
    for (int i = 0; i < 2; i++)
        #pragma unroll
        for (int r = 0; r < 4; r++) {
            int t = 16*i + kq*4 + r;
            #pragma unroll
            for (int j = 0; j < 4; j++)
                yb[(size_t)t * DINNER + 16*j + lrow] = accY[i][j][r];
        }
    #pragma unroll
    for (int i = 0; i < 4; i++)
        #pragma unroll
        for (int r = 0; r < 4; r++) {
            int p = 16*i + kq*4 + r;
            #pragma unroll
            for (int j = 0; j < 4; j++)
                Sc[((size_t)(bh * 4 + j) * NCHUNK + c) * 1024 + p * 16 + lrow] = accS[i][j][r];
        }
    if (lane == 0) Ptot[bh * NCHUNK + c] = __expf(Ah * cumTot);
}

// ----------------------- chunked SSM scan: combine -------------------------
__global__ __launch_bounds__(64) void scan_combine(
    const float* __restrict__ Sc, const float* __restrict__ Ptot,
    float* __restrict__ Sinit)
{
    int blk = blockIdx.x;
    int bh = blk >> 2;
    int p = threadIdx.x;
    float carry[16];
    #pragma unroll
    for (int j = 0; j < 16; j++) carry[j] = 0.f;
    for (int c = 0; c < NCHUNK; ++c) {
        size_t row = ((size_t)blk * NCHUNK + c) * 1024 + p * 16;
        float* o = Sinit + row;
        #pragma unroll
        for (int j = 0; j < 16; j++) o[j] = carry[j];
        float P = Ptot[bh * NCHUNK + c];
        const float* si = Sc + row;
        #pragma unroll
        for (int j = 0; j < 16; j++) carry[j] = fmaf(carry[j], P, si[j]);
    }
}

// -------------------- MFMA chunk scan: pass 2 ------------------------------
// block = (b*16+h)*32 + c, 64 thr. Yinter = (dAcum_t*C_t)·Sinit^T -> yp1.
// M=32 t, N=64 p, K=64 n. Sinit read f32 (coalesced) and converted in-reg.
__global__ __launch_bounds__(64) void scan_mfma2(
    const float* __restrict__ convout, const float* __restrict__ dtbuf,
    const float* __restrict__ A_log, const float* __restrict__ Sinit,
    float* __restrict__ yp1)
{
    __shared__ u16 Clds2[32 * 72];   // dAcum-scaled C bf16 [t][n]
    __shared__ float dtl[32], dacl[32];
    int blk = blockIdx.x;
    int c   = blk & 31;
    int bh  = blk >> 5;
    int b = bh >> 4, h = bh & 15;
    int lane = threadIdx.x;
    int lrow = lane & 15, kq = lane >> 4;
    size_t base = ((size_t)b * LL + (size_t)c * CHUNK) * CONVDIM;
    float Ah = -__expf(A_log[h]);

    if (lane < 32)
        dtl[lane] = dtbuf[((size_t)b * LL + (size_t)c * CHUNK + lane) * NHEADS + h];
    __syncthreads();
    float s_inc = 0.f;
    #pragma unroll
    for (int j = 0; j < 32; ++j) {
        float v = dtl[j];
        if (j <= lane) s_inc += v;
    }
    if (lane < 32) dacl[lane] = __expf(Ah * s_inc);
    __syncthreads();
    #pragma unroll
    for (int it = 0; it < 8; ++it) {            // 512 float4s of C
        int idx = it * 64 + lane;
        int t = idx >> 4, q = idx & 15;
        float sc = dacl[t];
        float4 v = *reinterpret_cast<const float4*>(
            &convout[base + (size_t)t * CONVDIM + DINNER + DSTATE + q * 4]);
        ushort4 r4;
        r4.x = f2bf(v.x * sc); r4.y = f2bf(v.y * sc);
        r4.z = f2bf(v.z * sc); r4.w = f2bf(v.w * sc);
        *reinterpret_cast<ushort4*>(&Clds2[t * 72 + q * 4]) = r4;
    }
    __syncthreads();

    f32x4 accI[2][4];
    #pragma unroll
    for (int i = 0; i < 2; i++)
        #pragma unroll
        for (int j = 0; j < 4; j++) {
            accI[i][j][0]=0.f; accI[i][j][1]=0.f; accI[i][j][2]=0.f; accI[i][j][3]=0.f;
        }
    #pragma unroll
    for (int ks = 0; ks < 2; ++ks) {
        bf16x8 ca[2];
        #pragma unroll
        for (int i = 0; i < 2; i++)
            ca[i] = *reinterpret_cast<const bf16x8*>(&Clds2[(16*i + lrow) * 72 + ks*32 + kq*8]);
        int nq = ks * 2 + (kq >> 1);
        int off = (kq & 1) * 8;
        #pragma unroll
        for (int j = 0; j < 4; j++) {
            int p = 16*j + lrow;
            const float* sp = Sinit + ((size_t)(bh * 4 + nq) * NCHUNK + c) * 1024 + p * 16 + off;
            float4 a = *reinterpret_cast<const float4*>(sp);
            float4 b4 = *reinterpret_cast<const float4*>(sp + 4);
            union { u16 us[8]; bf16x8 v; } fr;
            fr.us[0] = f2bf(a.x);  fr.us[1] = f2bf(a.y);
            fr.us[2] = f2bf(a.z);  fr.us[3] = f2bf(a.w);
            fr.us[4] = f2bf(b4.x); fr.us[5] = f2bf(b4.y);
            fr.us[6] = f2bf(b4.z); fr.us[7] = f2bf(b4.w);
            #pragma unroll
            for (int i = 0; i < 2; i++)
                accI[i][j] = __builtin_amdgcn_mfma_f32_16x16x32_bf16(ca[i], fr.v, accI[i][j], 0, 0, 0);
        }
    }

    float* yb = yp1 + ((size_t)b * LL + (size_t)c * CHUNK) * DINNER + h * HEADDIM;
    #pragma unroll
    for (int i = 0; i < 2; i++)
        #pragma unroll
        for (int r = 0; r < 4; r++) {
            int t = 16*i + kq*4 + r;
            #pragma unroll
            for (int j = 0; j < 4; j++)
                yb[(size_t)t * DINNER + 16*j + lrow] = accI[i][j][r];
        }
}

// ------------- gated RMSNorm (yp0+yp1+xD)*silu(z), bf16 out ----------------
__global__ __launch_bounds__(256) void gated_rms_kernel(
    const float* __restrict__ yp0, const float* __restrict__ yp1,
    const float* __restrict__ convout, const float* __restrict__ zx,
    const float* __restrict__ Dv, const float* __restrict__ norm_w,
    u16* __restrict__ gout)
{
    int bl = blockIdx.x;
    int c = threadIdx.x * 4;
    float4 y0 = *reinterpret_cast<const float4*>(yp0 + (size_t)bl * DINNER + c);
    float4 y1 = *reinterpret_cast<const float4*>(yp1 + (size_t)bl * DINNER + c);
    float4 xv = *reinterpret_cast<const float4*>(convout + (size_t)bl * CONVDIM + c);
    float4 zv = *reinterpret_cast<const float4*>(zx + (size_t)bl * NPROJ_PAD + c);
    float Dh = Dv[c >> 6];
    float g0 = (y0.x + y1.x + xv.x * Dh) * silu_f(zv.x);
    float g1 = (y0.y + y1.y + xv.y * Dh) * silu_f(zv.y);
    float g2 = (y0.z + y1.z + xv.z * Dh) * silu_f(zv.z);
    float g3 = (y0.w + y1.w + xv.w * Dh) * silu_f(zv.w);
    float tot = block_sum(g0 * g0 + g1 * g1 + g2 * g2 + g3 * g3);
    float sc = rsqrtf(tot * (1.f / DINNER) + 1e-5f);
    float4 nw = *reinterpret_cast<const float4*>(norm_w + c);
    ushort4 o;
    o.x = f2bf(g0 * sc * nw.x); o.y = f2bf(g1 * sc * nw.y);
    o.z = f2bf(g2 * sc * nw.z); o.w = f2bf(g3 * sc * nw.w);
    *reinterpret_cast<ushort4*>(gout + (size_t)bl * DINNER + c) = o;
}

// ---- residual + 4 split-K partials + RMSNorm (no weight), f32 out ---------
__global__ void residual_rms_sk_kernel(
    const float* __restrict__ a, const float* __restrict__ pbuf,
    float* __restrict__ outf, int ncols, int rows)
{
    int row = blockIdx.x;
    int c = threadIdx.x * 4;
    size_t slice = (size_t)rows * ncols;
    size_t off = (size_t)row * ncols + c;
    float4 va = *reinterpret_cast<const float4*>(a + off);
    float4 p0 = *reinterpret_cast<const float4*>(pbuf + off);
    float4 p1 = *reinterpret_cast<const float4*>(pbuf + slice + off);
    float4 p2 = *reinterpret_cast<const float4*>(pbuf + 2 * slice + off);
    float4 p3 = *reinterpret_cast<const float4*>(pbuf + 3 * slice + off);
    float v0 = va.x + ((p0.x + p1.x) + (p2.x + p3.x));
    float v1 = va.y + ((p0.y + p1.y) + (p2.y + p3.y));
    float v2 = va.z + ((p0.z + p1.z) + (p2.z + p3.z));
    float v3 = va.w + ((p0.w + p1.w) + (p2.w + p3.w));
    float tot = block_sum(v0 * v0 + v1 * v1 + v2 * v2 + v3 * v3);
    float sc = rsqrtf(tot / (float)ncols + 1e-5f);
    float4 o; o.x = v0 * sc; o.y = v1 * sc; o.z = v2 * sc; o.w = v3 * sc;
    *reinterpret_cast<float4*>(outf + off) = o;
}

// ------------- transpose per batch: in (R,C) -> out (C,R), dual write ------
__global__ __launch_bounds__(256) void transpose_dual_kernel(
    const float* __restrict__ in, u16* __restrict__ outb,
    float* __restrict__ outf, int R, int C)
{
    __shared__ float tile[32][33];
    int b = blockIdx.z;
    int c0 = blockIdx.x * 32, r0 = blockIdx.y * 32;
    const float* ip = in + (size_t)b * R * C;
    for (int i = threadIdx.y; i < 32; i += 8)
        tile[i][threadIdx.x] = ip[(size_t)(r0 + i) * C + c0 + threadIdx.x];
    __syncthreads();
    size_t ob = (size_t)b * R * C;
    for (int i = threadIdx.y; i < 32; i += 8) {
        float v = tile[threadIdx.x][i];
        size_t oi = ob + (size_t)(c0 + i) * R + r0 + threadIdx.x;
        outf[oi] = v;
        outb[oi] = f2bf(v);
    }
}

// ---------------------------------------------------------------------------
extern "C" void kernel_launch(void* const* d_in, const int* in_sizes, int n_in,
                              void* d_out, int out_size, void* d_ws, size_t ws_size,
                              hipStream_t stream)
{
    const float* hid      = (const float*)d_in[0];
    const float* in_proj  = (const float*)d_in[1];
    const float* conv_w   = (const float*)d_in[2];
    const float* conv_b   = (const float*)d_in[3];
    const float* dt_bias  = (const float*)d_in[4];
    const float* A_log    = (const float*)d_in[5];
    const float* Dv       = (const float*)d_in[6];
    const float* norm_w   = (const float*)d_in[7];
    const float* out_proj = (const float*)d_in[8];
    const float* gu_t     = (const float*)d_in[9];
    const float* down_t   = (const float*)d_in[10];
    const float* gu_m     = (const float*)d_in[11];
    const float* down_m   = (const float*)d_in[12];
    float* outp = (float*)d_out;

    char* ws = (char*)d_ws;
    u16* bf        = (u16*)ws;
    u16* hid_bf    = bf;
    u16* w_inproj  = bf + HID_E;
    u16* w_outproj = w_inproj + INPROJ_P_E;
    u16* w_gut     = w_outproj + OUTPROJ_E;
    u16* w_downt   = w_gut + GUT_E;
    u16* w_gum     = w_downt + DOWNT_E;
    u16* w_downm   = w_gum + GUM_E;
    size_t o = (size_t)(CONV_TOT_E * 2);
    auto alloc = [&](size_t bytes) { size_t r = o; o = (o + bytes + 255) & ~(size_t)255; return r; };
    size_t dt_off  = alloc(4096 * 16 * 4);
    size_t g_off   = alloc((size_t)4096 * 1024 * 2);
    size_t h1_off  = alloc((size_t)4096 * 512 * 4);
    size_t Pt_off  = alloc(2048 * 4);
    // ---- MLP region (live step 8+); Sc/Sinit OVERLAY it (live steps 4-5).
    size_t xtb_off = alloc((size_t)2048 * 1024 * 2);
    size_t xtf_off = alloc((size_t)2048 * 1024 * 4);
    size_t act1_off= alloc((size_t)2048 * 2816 * 2);
    size_t x2_off  = alloc((size_t)2048 * 1024 * 4);
    size_t h2b_off = alloc((size_t)4096 * 512 * 2);
    size_t h2f_off = alloc((size_t)4096 * 512 * 4);
    size_t act2_off= alloc((size_t)4096 * 1536 * 2);
    size_t pad_off = alloc((size_t)10 * 1024 * 1024);
    size_t Sc_off  = xtb_off;                          // 33.55 MB
    size_t Si_off  = xtb_off + (size_t)8192 * 1024 * 4;// 33.55 MB
    (void)pad_off;
    size_t R_off   = o;
    size_t zx_off  = R_off;
    size_t cv_off  = zx_off + (size_t)4096 * NPROJ_PAD * 4;
    size_t y_off   = cv_off + (size_t)4096 * CONVDIM * 4;
    size_t sk_off  = R_off;

    float* zx      = (float*)(ws + zx_off);
    float* convout = (float*)(ws + cv_off);
    float* ybuf    = (float*)(ws + y_off);           // yp0
    float* dtbuf   = (float*)(ws + dt_off);
    u16*   g_bf    = (u16*)(ws + g_off);
    float* h1      = (float*)(ws + h1_off);
    u16*   xt_bf   = (u16*)(ws + xtb_off);
    float* xt_f    = (float*)(ws + xtf_off);
    u16*   act1    = (u16*)(ws + act1_off);
    float* x2      = (float*)(ws + x2_off);
    u16*   h2_bf   = (u16*)(ws + h2b_off);
    float* h2_f    = (float*)(ws + h2f_off);
    u16*   act2    = (u16*)(ws + act2_off);
    float* skbuf   = (float*)(ws + sk_off);
    float* Sc      = (float*)(ws + Sc_off);          // yp1 after scan_combine
    float* Sinit   = (float*)(ws + Si_off);
    float* Ptot    = (float*)(ws + Pt_off);

    // 1) convert weights + hidden to bf16
    convert_all_kernel<<<14464, 256, 0, stream>>>(
        hid, in_proj, out_proj, gu_t, down_t, gu_m, down_m, bf);

    // 2) zxbcdt = hidden @ in_proj^T
    gemm_bt<<<dim3(NPROJ_PAD / 128, 4096 / 128), 256, 0, stream>>>(
        hid_bf, w_inproj, zx, 4096, NPROJ_PAD, 512);

    // 3) conv + dt
    conv_dt_kernel<<<18688, 256, 0, stream>>>(zx, conv_w, conv_b, dt_bias, convout, dtbuf);

    // 4) MFMA chunk scan
    scan_mfma1<<<2048, 64, 0, stream>>>(convout, dtbuf, A_log, Sc, Ptot, ybuf);
    scan_combine<<<256, 64, 0, stream>>>(Sc, Ptot, Sinit);
    scan_mfma2<<<2048, 64, 0, stream>>>(convout, dtbuf, A_log, Sinit, Sc);

    // 5) gated RMSNorm -> bf16
    gated_rms_kernel<<<4096, 256, 0, stream>>>(ybuf, Sc, convout, zx, Dv, norm_w, g_bf);

    // 6) out_proj GEMM, split-K x4 -> partials in skbuf
    gemm_bt_sk<<<dim3(512 / 128, 4096 / 128, 4), 256, 0, stream>>>(
        g_bf, w_outproj, skbuf, 4096, 512, 1024, 256);

    // 7) h1 = rms(hidden + sum partials)
    residual_rms_sk_kernel<<<4096, 128, 0, stream>>>(hid, skbuf, h1, 512, 4096);

    // 8) transpose (B,1024,512) -> (B,512,1024)
    transpose_dual_kernel<<<dim3(16, 32, 4), dim3(32, 8), 0, stream>>>(h1, xt_bf, xt_f, 1024, 512);

    // 9) token MLP fused: act1 = swiglu(xt @ gu_t^T)
    gemm_swiglu<<<dim3(INTER_T / 64, 2048 / 128), 256, 0, stream>>>(
        xt_bf, w_gut, act1, 2048, INTER_T, 1024);

    // 10) down_t GEMM, split-K x4 -> partials in skbuf
    gemm_bt_sk<<<dim3(1024 / 128, 2048 / 128, 4), 256, 0, stream>>>(
        act1, w_downt, skbuf, 2048, 1024, 2816, 704);

    // 11) x2 = rms(xt_f + sum partials)
    residual_rms_sk_kernel<<<2048, 256, 0, stream>>>(xt_f, skbuf, x2, 1024, 2048);

    // 12) transpose back (B,512,1024) -> (B,1024,512)
    transpose_dual_kernel<<<dim3(32, 16, 4), dim3(32, 8), 0, stream>>>(x2, h2_bf, h2_f, 512, 1024);

    // 13) channel MLP fused: act2 = swiglu(h2 @ gu_m^T)
    gemm_swiglu<<<dim3(INTER_M / 64, 4096 / 128), 256, 0, stream>>>(
        h2_bf, w_gum, act2, 4096, INTER_M, 512);

    // 14) down_m GEMM, split-K x4 -> partials in skbuf
    gemm_bt_sk<<<dim3(512 / 128, 4096 / 128, 4), 256, 0, stream>>>(
        act2, w_downm, skbuf, 4096, 512, 1536, 384);

    // 15) out = rms(h2_f + sum partials)
    residual_rms_sk_kernel<<<4096, 128, 0, stream>>>(h2_f, skbuf, outp, 512, 4096);
}